// Round 16
// baseline (209.350 us; speedup 1.0000x reference)
//
#include <hip/hip_runtime.h>
#include <stdint.h>

typedef _Float16 h8v __attribute__((ext_vector_type(8)));
typedef float f4v __attribute__((ext_vector_type(4)));

#define MFMA(a,b,c) __builtin_amdgcn_mfma_f32_16x16x32_f16((a),(b),(c),0,0,0)
#define NSPLIT 2

__device__ __forceinline__ _Float16 f2h(float f) { return (_Float16)f; }

// swizzled byte offset: row pitch 64B, 4 chunks of 16B, XOR on (row>>1)&3
__device__ __forceinline__ int swb(int row, int chunk) {
  return row * 64 + (((chunk) ^ ((row >> 1) & 3)) << 4);
}

// P-LDS swizzle (attn)
__device__ __forceinline__ int pswb(int q, int sxb) {
  return q * 128 + (sxb ^ (((q >> 2) & 3) << 5));
}

// async global->LDS, 16B per lane; LDS dest = base + lane*16 (wave-uniform base)
__device__ __forceinline__ void gload16(const void* g, void* l) {
  __builtin_amdgcn_global_load_lds((const __attribute__((address_space(1))) void*)g,
                                   (__attribute__((address_space(3))) void*)l, 16, 0, 0);
}

// ---------------- K1: PE add + transpose:  xpe_t[b][t][c] = f16(x[b][c][t] + pe(t,c))
__global__ __launch_bounds__(256) void k_pe_t(const float* __restrict__ x, _Float16* __restrict__ xpe) {
  __shared__ float tile[32][33];
  int b = blockIdx.z;
  int t0 = blockIdx.x * 32, c0 = blockIdx.y * 32;
  int tid = threadIdx.x;
  int col = tid & 31, rowq = tid >> 5;
#pragma unroll
  for (int i = 0; i < 4; ++i) {
    int c = c0 + rowq + i * 8;
    int t = t0 + col;
    int j2 = c & ~1;
    float dv = expf(-0.01798894603885192f * (float)j2);  // ln(1e4)/512
    float ang = (float)t * dv;
    float pe = (c & 1) ? cosf(ang) : sinf(ang);
    tile[rowq + i * 8][col] = x[((size_t)b * 512 + c) * 2048 + t] + pe;
  }
  __syncthreads();
#pragma unroll
  for (int i = 0; i < 4; ++i) {
    int t = t0 + rowq + i * 8;
    int c = c0 + col;
    xpe[((size_t)b * 2048 + t) * 512 + c] = f2h(tile[col][rowq + i * 8]);
  }
}

// ---------------- K2: fused prep — proj-weight casts, z_w cast, tconv weight transpose
__global__ __launch_bounds__(256) void k_prep(const float* __restrict__ thw, const float* __restrict__ phw,
                                              const float* __restrict__ gw,  const float* __restrict__ Ww,
                                              const float* __restrict__ zw,
                                              const float* __restrict__ w1, const float* __restrict__ w2,
                                              _Float16* __restrict__ wc, _Float16* __restrict__ zh,
                                              _Float16* __restrict__ wt) {
  int task = blockIdx.x;
  int tid = threadIdx.x;
  if (task < 2048) {
    int w = task >> 9;
    const float* s = (w == 0) ? thw : (w == 1) ? phw : (w == 2) ? gw : Ww;
    int i = (task & 511) * 256 + tid;
    wc[(size_t)w * 131072 + i] = f2h(s[i]);
  } else if (task < 5120) {
    int i = (task - 2048) * 256 + tid;
    zh[i] = f2h(zw[i]);
  } else {
    int wb = task - 5120;
    int z = wb >> 6;
    const float* src = (z < 3) ? w1 : w2;
    int k = (z < 3) ? z : z - 3;
    __shared__ _Float16 tile[64][65];
    int m0 = ((wb & 63) >> 3) * 64, c0 = (wb & 7) * 64;
    int tc = tid & 63, tm = tid >> 6;
#pragma unroll
    for (int i = 0; i < 16; ++i) {
      int m = m0 + tm + i * 4;
      tile[tm + i * 4][tc] = f2h(src[(size_t)m * 1536 + (size_t)k * 512 + c0 + tc]);
    }
    __syncthreads();
#pragma unroll
    for (int i = 0; i < 16; ++i) {
      int c = c0 + tm + i * 4;
      wt[((size_t)z * 512 + c) * 512 + m0 + tc] = tile[tc][tm + i * 4];
    }
  }
}

// ---------------- K3: merge conv weights through z (f16 MFMA)
__global__ __launch_bounds__(256) void k_merge(const _Float16* __restrict__ zh,
                                               const _Float16* __restrict__ wt,
                                               const float* __restrict__ zwf,
                                               _Float16* __restrict__ M) {
  int s = blockIdx.z;
  int wid = threadIdx.x >> 6, lane = threadIdx.x & 63;
  int o0 = blockIdx.y * 64 + (wid >> 1) * 32;
  int c0 = blockIdx.x * 64 + (wid & 1) * 32;
  int row16 = lane & 15, kg = lane >> 4, koff = kg * 8;
  f4v acc[2][2];
#pragma unroll
  for (int mi = 0; mi < 2; ++mi)
#pragma unroll
    for (int ni = 0; ni < 2; ++ni) acc[mi][ni] = (f4v){0.f, 0.f, 0.f, 0.f};

  int np = (s == 2) ? 2 : 1;
  for (int p = 0; p < np; ++p) {
    int seg, wi;
    if (s == 0)      { seg = 1024; wi = 3; }
    else if (s == 1) { seg = 512;  wi = 0; }
    else if (s == 3) { seg = 512;  wi = 2; }
    else if (s == 4) { seg = 1024; wi = 5; }
    else             { seg = (p == 0) ? 512 : 1024; wi = (p == 0) ? 1 : 4; }
    const _Float16* A = zh + seg;
    const _Float16* B = wt + (size_t)wi * 512 * 512;
    for (int k0 = 0; k0 < 512; k0 += 32) {
      h8v a[2], bv[2];
#pragma unroll
      for (int i = 0; i < 2; ++i)
        a[i] = *(const h8v*)(A + (size_t)(o0 + i * 16 + row16) * 1536 + k0 + koff);
#pragma unroll
      for (int i = 0; i < 2; ++i)
        bv[i] = *(const h8v*)(B + (size_t)(c0 + i * 16 + row16) * 512 + k0 + koff);
#pragma unroll
      for (int mi = 0; mi < 2; ++mi)
#pragma unroll
        for (int ni = 0; ni < 2; ++ni)
          acc[mi][ni] = MFMA(a[mi], bv[ni], acc[mi][ni]);
    }
  }
  _Float16* dst = M + (size_t)s * 512 * 512;
#pragma unroll
  for (int mi = 0; mi < 2; ++mi)
#pragma unroll
    for (int r = 0; r < 4; ++r) {
      int o = o0 + mi * 16 + kg * 4 + r;
#pragma unroll
      for (int ni = 0; ni < 2; ++ni) {
        int c = c0 + ni * 16 + row16;
        float v = acc[mi][ni][r];
        if (s == 2) v += zwf[(size_t)o * 1536 + c];
        dst[(size_t)o * 512 + c] = f2h(v);
      }
    }
}

// ---------------- shared 128x128 TN GEMM, BOTH operands staged via global_load_lds
__device__ __forceinline__ void gemm128_glds(const _Float16* __restrict__ L, int ldl,
                                             const _Float16* __restrict__ R, int ldr,
                                             int K, int tid, char* lsA, char* lsB,
                                             f4v acc[4][4]) {
  int wid = tid >> 6, lane = tid & 63;
  int wm = (wid >> 1) * 64, wn = (wid & 1) * 64;
  int row16 = lane & 15, kg = lane >> 4;
  int j0 = tid, j1 = tid + 256;
  int r0 = j0 >> 2, c0 = (j0 & 3) ^ ((j0 >> 3) & 3);
  int r1 = j1 >> 2, c1 = (j1 & 3) ^ ((j1 >> 3) & 3);
  const _Float16* La0 = L + (size_t)r0 * ldl + c0 * 8;
  const _Float16* La1 = L + (size_t)r1 * ldl + c1 * 8;
  const _Float16* Rb0 = R + (size_t)r0 * ldr + c0 * 8;
  const _Float16* Rb1 = R + (size_t)r1 * ldr + c1 * 8;
  char* dA0 = lsA + wid * 1024;
  char* dA1 = lsA + 4096 + wid * 1024;
  char* dB0 = lsB + wid * 1024;
  char* dB1 = lsB + 4096 + wid * 1024;

  gload16(La0, dA0); gload16(La1, dA1);
  gload16(Rb0, dB0); gload16(Rb1, dB1);
  __syncthreads();

  int nk = K >> 5;
  for (int kc = 0; kc < nk; ++kc) {
    char* ca = lsA + (kc & 1) * 8192;
    char* cb = lsB + (kc & 1) * 8192;
    if (kc < nk - 1) {
      int k1 = (kc + 1) << 5;
      int off = ((kc + 1) & 1) * 8192;
      gload16(La0 + k1, dA0 + off); gload16(La1 + k1, dA1 + off);
      gload16(Rb0 + k1, dB0 + off); gload16(Rb1 + k1, dB1 + off);
    }
    h8v a[4], bv[4];
#pragma unroll
    for (int i = 0; i < 4; ++i)
      a[i] = *(const h8v*)(ca + swb(wm + i * 16 + row16, kg));
#pragma unroll
    for (int i = 0; i < 4; ++i)
      bv[i] = *(const h8v*)(cb + swb(wn + i * 16 + row16, kg));
#pragma unroll
    for (int mi = 0; mi < 4; ++mi)
#pragma unroll
      for (int ni = 0; ni < 4; ++ni)
        acc[mi][ni] = MFMA(a[mi], bv[ni], acc[mi][ni]);
    __syncthreads();
  }
}

// ---------------- K4: conv GEMM  x2[o][t] = sum_s M_s[o][:]·xpe[t+s-2][:] + zb
// 1-D grid 1024, XCD-affine: b = bid&7 (all blocks of batch b on one XCD)
__global__ __launch_bounds__(256, 2) void k_conv(const _Float16* __restrict__ Mh,
                                                 const _Float16* __restrict__ xpe,
                                                 const float* __restrict__ zb,
                                                 _Float16* __restrict__ x2ct,
                                                 _Float16* __restrict__ x2h) {
  int bid = blockIdx.x;
  int b = bid & 7;
  int j = bid >> 3;                 // 0..127
  int t0 = (j & 15) * 128, o0 = (j >> 4) * 64;
  int tid = threadIdx.x;
  int wid = tid >> 6, lane = tid & 63;
  int wm = (wid >> 1) * 32, wn = (wid & 1) * 64;
  int row16 = lane & 15, kg = lane >> 4;
  __shared__ __align__(16) char asm2[2][320 * 64];
  __shared__ __align__(16) char bsm[2][132 * 64];
  const _Float16* Xb = xpe + (size_t)b * 2048 * 512;
  const h8v zerov = {0, 0, 0, 0, 0, 0, 0, 0};

  f4v acc[2][4];
#pragma unroll
  for (int mi = 0; mi < 2; ++mi)
#pragma unroll
    for (int ni = 0; ni < 4; ++ni) acc[mi][ni] = (f4v){0.f, 0.f, 0.f, 0.f};

  const _Float16* Asrc[5];
#pragma unroll
  for (int p = 0; p < 5; ++p) {
    int jj = tid + 256 * p;
    int row = jj >> 2, c = (jj & 3) ^ ((jj >> 3) & 3);
    Asrc[p] = Mh + (size_t)(row >> 6) * 262144 + (size_t)(o0 + (row & 63)) * 512 + c * 8;
  }
  int achk = tid & 3;
  int br0 = tid >> 2, br1 = (tid + 256) >> 2, br2 = (tid + 512) >> 2;
  int tg0 = t0 + br0 - 2, tg1 = t0 + br1 - 2, tg2 = t0 + br2 - 2;
  bool v0 = (tg0 >= 0 && tg0 < 2048);
  bool v1 = (tg1 >= 0 && tg1 < 2048);
  bool v2 = (tid < 16) && (tg2 >= 0 && tg2 < 2048);
  h8v s0, s1, s2;

#pragma unroll
  for (int p = 0; p < 5; ++p)
    gload16(Asrc[p], (char*)asm2[0] + p * 4096 + wid * 1024);
  s0 = v0 ? *(const h8v*)(Xb + (size_t)tg0 * 512 + achk * 8) : zerov;
  s1 = v1 ? *(const h8v*)(Xb + (size_t)tg1 * 512 + achk * 8) : zerov;
  s2 = v2 ? *(const h8v*)(Xb + (size_t)tg2 * 512 + achk * 8) : zerov;
  *(h8v*)(&bsm[0][swb(br0, achk)]) = s0;
  *(h8v*)(&bsm[0][swb(br1, achk)]) = s1;
  if (tid < 16) *(h8v*)(&bsm[0][swb(br2, achk)]) = s2;
  __syncthreads();

  for (int kc = 0; kc < 16; ++kc) {
    char* ca = asm2[kc & 1];
    char* cb = bsm[kc & 1];
    bool pf = (kc < 15);
    if (pf) {
      int k1 = (kc + 1) * 32;
      char* nbase = (char*)asm2[(kc & 1) ^ 1];
#pragma unroll
      for (int p = 0; p < 5; ++p)
        gload16(Asrc[p] + k1, nbase + p * 4096 + wid * 1024);
      s0 = v0 ? *(const h8v*)(Xb + (size_t)tg0 * 512 + k1 + achk * 8) : zerov;
      s1 = v1 ? *(const h8v*)(Xb + (size_t)tg1 * 512 + k1 + achk * 8) : zerov;
      s2 = v2 ? *(const h8v*)(Xb + (size_t)tg2 * 512 + k1 + achk * 8) : zerov;
    }
#pragma unroll
    for (int s = 0; s < 5; ++s) {
      h8v a[2];
#pragma unroll
      for (int i = 0; i < 2; ++i)
        a[i] = *(const h8v*)(ca + swb(s * 64 + wm + i * 16 + row16, kg));
#pragma unroll
      for (int ni = 0; ni < 4; ++ni) {
        int rr = wn + ni * 16 + row16 + s;
        h8v bv = *(const h8v*)(cb + swb(rr, kg));
#pragma unroll
        for (int mi = 0; mi < 2; ++mi)
          acc[mi][ni] = MFMA(a[mi], bv, acc[mi][ni]);
      }
    }
    if (pf) {
      char* nb = bsm[(kc & 1) ^ 1];
      *(h8v*)(&nb[swb(br0, achk)]) = s0;
      *(h8v*)(&nb[swb(br1, achk)]) = s1;
      if (tid < 16) *(h8v*)(&nb[swb(br2, achk)]) = s2;
    }
    __syncthreads();
  }

#pragma unroll
  for (int mi = 0; mi < 2; ++mi)
#pragma unroll
    for (int r = 0; r < 4; ++r) {
      int o = o0 + wm + mi * 16 + kg * 4 + r;
      float bias = zb[o];
#pragma unroll
      for (int ni = 0; ni < 4; ++ni) {
        int t = t0 + wn + ni * 16 + row16;
        float v = acc[mi][ni][r] + bias;
        x2ct[((size_t)b * 512 + o) * 2048 + t] = f2h(v);
        x2h[((size_t)b * 2048 + t) * 512 + o] = f2h(v);
      }
    }
}

// ---------------- K5: g/theta/phi projections; 1-D grid 768, XCD-affine on b
__global__ __launch_bounds__(256, 3) void k_gtp(const _Float16* __restrict__ x2h,
                                                const _Float16* __restrict__ wth, const _Float16* __restrict__ wph,
                                                const _Float16* __restrict__ wg,
                                                const float* __restrict__ thb, const float* __restrict__ phb,
                                                const float* __restrict__ gb,
                                                _Float16* __restrict__ tht, _Float16* __restrict__ pht,
                                                _Float16* __restrict__ gv) {
  int bid = blockIdx.x;
  int b = bid & 7;
  int j = bid >> 3;                 // 0..95
  int bx = j & 15, by = j >> 4;     // by 0..5
  int proj = by >> 1, dtile = by & 1;
  int tid = threadIdx.x;
  int wid = tid >> 6, lane = tid & 63;
  int wm = (wid >> 1) * 64, wn = (wid & 1) * 64;
  int row16 = lane & 15, kg = lane >> 4;
  __shared__ __align__(16) char lA[2][8192];
  __shared__ __align__(16) char lB[2][8192];
  const _Float16* X = x2h + (size_t)b * 2048 * 512;
  f4v acc[4][4];
#pragma unroll
  for (int mi = 0; mi < 4; ++mi)
#pragma unroll
    for (int ni = 0; ni < 4; ++ni) acc[mi][ni] = (f4v){0.f, 0.f, 0.f, 0.f};

  if (proj < 2) {
    const _Float16* W = (proj == 0) ? wth : wph;
    const float* bias = (proj == 0) ? thb : phb;
    _Float16* out = (proj == 0) ? tht : pht;
    int m0 = bx * 128, n0 = dtile * 128;
    gemm128_glds(X + (size_t)m0 * 512, 512, W + (size_t)n0 * 512, 512, 512, tid, lA[0], lB[0], acc);
#pragma unroll
    for (int mi = 0; mi < 4; ++mi)
#pragma unroll
      for (int r = 0; r < 4; ++r) {
        int t = m0 + wm + mi * 16 + kg * 4 + r;
#pragma unroll
        for (int ni = 0; ni < 4; ++ni) {
          int d = n0 + wn + ni * 16 + row16;
          out[((size_t)b * 2048 + t) * 256 + d] = f2h(acc[mi][ni][r] + bias[d]);
        }
      }
  } else {
    int m0 = dtile * 128, n0 = bx * 128;
    gemm128_glds(wg + (size_t)m0 * 512, 512, X + (size_t)n0 * 512, 512, 512, tid, lA[0], lB[0], acc);
#pragma unroll
    for (int mi = 0; mi < 4; ++mi)
#pragma unroll
      for (int r = 0; r < 4; ++r) {
        int d = m0 + wm + mi * 16 + kg * 4 + r;
        float bias = gb[d];
#pragma unroll
        for (int ni = 0; ni < 4; ++ni) {
          int t = n0 + wn + ni * 16 + row16;
          gv[((size_t)b * 256 + d) * 2048 + t] = f2h(acc[mi][ni][r] + bias);
        }
      }
  }
}

// ---------------- K6: flash attention; 1-D grid 256, XCD-affine on (sp,b) group
__global__ __launch_bounds__(512) void k_attn(const _Float16* __restrict__ tht,
                                              const _Float16* __restrict__ pht,
                                              const _Float16* __restrict__ gv,
                                              _Float16* __restrict__ yp,
                                              float* __restrict__ mlm, float* __restrict__ mll) {
  int bid = blockIdx.x;
  int grp = (bid & 7) + 8 * ((bid >> 3) >> 4);   // 0..15 — XCD r serves groups {r, r+8}
  int qt  = (bid >> 3) & 15;
  int sp = grp & 1, b = grp >> 1;
  int tid = threadIdx.x;
  int wid = tid >> 6, lane = tid & 63;
  int q0 = qt * 128 + wid * 16;
  int row16 = lane & 15, kg = lane >> 4, koff = kg * 8;
  int rswz = row16 & 7;

  __shared__ __align__(16) _Float16 kvbuf[32768];
  __shared__ __align__(16) _Float16 p_lds[8][1024];
  char* pw = (char*)&p_lds[wid][0];
  char* cb = (char*)&kvbuf[0];

  const _Float16* thb = tht + (size_t)b * 2048 * 256;
  const _Float16* phb = pht + (size_t)b * 2048 * 256;
  const _Float16* gvb = gv + (size_t)b * 256 * 2048;

  h8v qf[8];
#pragma unroll
  for (int ks = 0; ks < 8; ++ks)
    qf[ks] = *(const h8v*)(thb + (size_t)(q0 + row16) * 256 + ks * 32 + koff);

  float m_i[4], l_i[4];
#pragma unroll
  for (int r = 0; r < 4; ++r) { m_i[r] = -3e38f; l_i[r] = 0.f; }
  f4v yacc[16];
#pragma unroll
  for (int ni = 0; ni < 16; ++ni) yacc[ni] = (f4v){0.f, 0.f, 0.f, 0.f};

  {
    int k0 = sp * 1024;
#pragma unroll
    for (int j = 0; j < 4; ++j) {
      int idx = tid + 512 * j;
      h8v kv = *(const h8v*)(phb + (size_t)(k0 + (idx >> 5)) * 256 + (idx & 31) * 8);
      h8v vv = *(const h8v*)(gvb + (size_t)(idx >> 3) * 2048 + k0 + (idx & 7) * 8);
      *(h8v*)(cb + (idx >> 5) * 512 + (((idx & 31) ^ ((idx >> 5) & 7)) << 4)) = kv;
      *(h8v*)(cb + 32768 + (idx >> 3) * 128 + (((idx & 7) ^ ((idx >> 3) & 7)) << 4)) = vv;
    }
  }
  __syncthreads();

  for (int t = 0; t < 16; ++t) {
    int k0 = sp * 1024 + t * 64;

    h8v kreg[4], vreg[4];
    bool pf = (t < 15);
    if (pf) {
      int k1 = k0 + 64;
#pragma unroll
      for (int j = 0; j < 4; ++j) {
        int idx = tid + 512 * j;
        kreg[j] = *(const h8v*)(phb + (size_t)(k1 + (idx >> 5)) * 256 + (idx & 31) * 8);
        vreg[j] = *(const h8v*)(gvb + (size_t)(idx >> 3) * 2048 + k1 + (idx & 7) * 8);
      }
    }

    f4v sacc[4];
#pragma unroll
    for (int ni = 0; ni < 4; ++ni) sacc[ni] = (f4v){0.f, 0.f, 0.f, 0.f};
#pragma unroll
    for (int ks = 0; ks < 8; ++ks) {
#pragma unroll
      for (int ni = 0; ni < 4; ++ni) {
        int krow = ni * 16 + row16;
        h8v kf = *(const h8v*)(cb + krow * 512 + ((((ks << 2) | kg) ^ rswz) << 4));
        sacc[ni] = MFMA(qf[ks], kf, sacc[ni]);
      }
    }
    float al[4] = {1.f, 1.f, 1.f, 1.f};
    float rmv[4];
    float nd = 0.f;
#pragma unroll
    for (int r = 0; r < 4; ++r) {
      float rm = fmaxf(fmaxf(sacc[0][r], sacc[1][r]), fmaxf(sacc[2][r], sacc[3][r]));
#pragma unroll
      for (int m = 1; m <= 8; m <<= 1) rm = fmaxf(rm, __shfl_xor(rm, m, 64));
      rmv[r] = rm;
      if (rm > m_i[r] + 8.f) nd = 1.f;
    }
    if (__any(nd != 0.f)) {
#pragma unroll
      for (int r = 0; r < 4; ++r) {
        float mn = fmaxf(m_i[r], rmv[r]);
        al[r] = __expf(m_i[r] - mn);
        m_i[r] = mn;
      }
#pragma unroll
      for (int ni = 0; ni < 16; ++ni)
#pragma unroll
        for (int r = 0; r < 4; ++r) yacc[ni][r] *= al[r];
    }
#pragma unroll
    for (int r = 0; r < 4; ++r) {
      float rs = 0.f;
#pragma unroll
      for (int ni = 0; ni < 4; ++ni) {
        float p = __expf(sacc[ni][r] - m_i[r]);
        sacc[ni][r] = p;
        rs += p;
      }
#pragma unroll
      for (int m = 1; m <= 8; m <<= 1) rs += __shfl_xor(rs, m, 64);
      l_i[r] = l_i[r] * al[r] + rs;
    }
#pragma unroll
    for (int r = 0; r < 4; ++r) {
      int q = kg * 4 + r;
#pragma unroll
      for (int ni = 0; ni < 4; ++ni) {
        int sx = ni * 16 + row16;
        *(_Float16*)(pw + pswb(q, sx * 2)) = f2h(sacc[ni][r]);
      }
    }
#pragma unroll
    for (int ks2 = 0; ks2 < 2; ++ks2) {
      h8v pa = *(const h8v*)(pw + pswb(row16, (ks2 * 32 + koff) * 2));
#pragma unroll
      for (int ni = 0; ni < 16; ++ni) {
        int d = ni * 16 + row16;
        h8v vb = *(const h8v*)(cb + 32768 + d * 128 + ((((ks2 << 2) | kg) ^ rswz) << 4));
        yacc[ni] = MFMA(pa, vb, yacc[ni]);
      }
    }
    if (pf) {
      __syncthreads();
#pragma unroll
      for (int j = 0; j < 4; ++j) {
        int idx = tid + 512 * j;
        *(h8v*)(cb + (idx >> 5) * 512 + (((idx & 31) ^ ((idx >> 5) & 7)) << 4)) = kreg[j];
        *(h8v*)(cb + 32768 + (idx >> 3) * 128 + (((idx & 7) ^ ((idx >> 3) & 7)) << 4)) = vreg[j];
      }
      __syncthreads();
    }
  }

  _Float16* yb = yp + (size_t)(sp * 8 + b) * 2048 * 256;
  float* mm = mlm + (size_t)(sp * 8 + b) * 2048;
  float* ml = mll + (size_t)(sp * 8 + b) * 2048;
#pragma unroll
  for (int r = 0; r < 4; ++r) {
    int q = q0 + kg * 4 + r;
#pragma unroll
    for (int ni = 0; ni < 16; ++ni)
      yb[(size_t)q * 256 + ni * 16 + row16] = f2h(yacc[ni][r]);
    if (row16 == 0) { mm[q] = m_i[r]; ml[q] = l_i[r]; }
  }
}

// ---------------- K7: out = BN(W@y + Wb) + x2; 1-D grid 512, XCD-affine on b
__global__ __launch_bounds__(256, 3) void k_final(const _Float16* __restrict__ Wh,
                                                  const _Float16* __restrict__ yp,
                                                  const float* __restrict__ mlm, const float* __restrict__ mll,
                                                  const float* __restrict__ Wb,
                                                  const float* __restrict__ bng, const float* __restrict__ bnb,
                                                  const float* __restrict__ bnm, const float* __restrict__ bnv,
                                                  const _Float16* __restrict__ x2ct, float* __restrict__ out) {
  int bid = blockIdx.x;
  int b = bid & 7;
  int j = bid >> 3;                 // 0..63
  int t0 = (j & 15) * 128, o0 = (j >> 4) * 128;
  int tid = threadIdx.x;
  int wid = tid >> 6, lane = tid & 63;
  int wm = (wid >> 1) * 64, wn = (wid & 1) * 64;
  int row16 = lane & 15, kg = lane >> 4;
  __shared__ __align__(16) char lA[2][8192];
  __shared__ __align__(16) char lB[2][8192];
  f4v acc[4][4];
#pragma unroll
  for (int mi = 0; mi < 4; ++mi)
#pragma unroll
    for (int ni = 0; ni < 4; ++ni) acc[mi][ni] = (f4v){0.f, 0.f, 0.f, 0.f};

  const _Float16* L = Wh + (size_t)o0 * 256;
  const _Float16* Y0 = yp + ((size_t)b * 2048 + t0) * 256;
  const _Float16* Y1 = yp + ((size_t)(8 + b) * 2048 + t0) * 256;
  int ar0 = tid >> 2, ar1 = ar0 + 64, ach = tid & 3;
  int j0 = tid, j1 = tid + 256;
  int gr0 = j0 >> 2, gc0 = (j0 & 3) ^ ((j0 >> 3) & 3);
  int gr1 = j1 >> 2, gc1 = (j1 & 3) ^ ((j1 >> 3) & 3);
  const _Float16* La0 = L + (size_t)gr0 * 256 + gc0 * 8;
  const _Float16* La1 = L + (size_t)gr1 * 256 + gc1 * 8;
  char* dA0 = lA[0] + wid * 1024;
  char* dA1 = lA[0] + 4096 + wid * 1024;

  float w0a, w1a, w0b, w1b;
  {
    int qa = t0 + ar0, qb = t0 + ar1;
    float mA0 = mlm[(size_t)b * 2048 + qa], mA1 = mlm[(size_t)(8 + b) * 2048 + qa];
    float Ma = fmaxf(mA0, mA1);
    float e0 = __expf(mA0 - Ma), e1 = __expf(mA1 - Ma);
    float La = e0 * mll[(size_t)b * 2048 + qa] + e1 * mll[(size_t)(8 + b) * 2048 + qa];
    float ia = 1.f / La;
    w0a = e0 * ia; w1a = e1 * ia;
    float mB0 = mlm[(size_t)b * 2048 + qb], mB1 = mlm[(size_t)(8 + b) * 2048 + qb];
    float Mb = fmaxf(mB0, mB1);
    float f0 = __expf(mB0 - Mb), f1 = __expf(mB1 - Mb);
    float Lb = f0 * mll[(size_t)b * 2048 + qb] + f1 * mll[(size_t)(8 + b) * 2048 + qb];
    float ib = 1.f / Lb;
    w0b = f0 * ib; w1b = f1 * ib;
  }

  h8v pb0, pb1;
  auto comb = [&](const _Float16* y0, const _Float16* y1, float w0, float w1) -> h8v {
    h8v u = *(const h8v*)y0, v = *(const h8v*)y1, o;
#pragma unroll
    for (int jj = 0; jj < 8; ++jj) o[jj] = f2h(w0 * (float)u[jj] + w1 * (float)v[jj]);
    return o;
  };

  gload16(La0, dA0); gload16(La1, dA1);
  pb0 = comb(Y0 + (size_t)ar0 * 256 + ach * 8, Y1 + (size_t)ar0 * 256 + ach * 8, w0a, w1a);
  pb1 = comb(Y0 + (size_t)ar1 * 256 + ach * 8, Y1 + (size_t)ar1 * 256 + ach * 8, w0b, w1b);
  *(h8v*)(lB[0] + swb(ar0, ach)) = pb0;
  *(h8v*)(lB[0] + swb(ar1, ach)) = pb1;
  __syncthreads();

  for (int kc = 0; kc < 8; ++kc) {
    char* ca = lA[kc & 1];
    char* cbp = lB[kc & 1];
    bool pf = (kc < 7);
    if (pf) {
      int k1 = (kc + 1) << 5;
      int off = ((kc + 1) & 1) * 8192;
      gload16(La0 + k1, dA0 + off); gload16(La1 + k1, dA1 + off);
      pb0 = comb(Y0 + (size_t)ar0 * 256 + k1 + ach * 8, Y1 + (size_t)ar0 * 256 + k1 + ach * 8, w0a, w1a);
      pb1 = comb(Y0 + (size_t)ar1 * 256 + k1 + ach * 8, Y1 + (size_t)ar1 * 256 + k1 + ach * 8, w0b, w1b);
    }
    h8v a[4], bv[4];
#pragma unroll
    for (int i = 0; i < 4; ++i)
      a[i] = *(const h8v*)(ca + swb(wm + i * 16 + row16, kg));
#pragma unroll
    for (int i = 0; i < 4; ++i)
      bv[i] = *(const h8v*)(cbp + swb(wn + i * 16 + row16, kg));
#pragma unroll
    for (int mi = 0; mi < 4; ++mi)
#pragma unroll
      for (int ni = 0; ni < 4; ++ni)
        acc[mi][ni] = MFMA(a[mi], bv[ni], acc[mi][ni]);
    if (pf) {
      char* nb = lB[(kc & 1) ^ 1];
      *(h8v*)(nb + swb(ar0, ach)) = pb0;
      *(h8v*)(nb + swb(ar1, ach)) = pb1;
    }
    __syncthreads();
  }

#pragma unroll
  for (int mi = 0; mi < 4; ++mi)
#pragma unroll
    for (int r = 0; r < 4; ++r) {
      int o = o0 + wm + mi * 16 + kg * 4 + r;
      float sc = bng[o] * rsqrtf(bnv[o] + 1e-5f);
      float add = (Wb[o] - bnm[o]) * sc + bnb[o];
#pragma unroll
      for (int ni = 0; ni < 4; ++ni) {
        int t = t0 + wn + ni * 16 + row16;
        size_t idx = ((size_t)b * 512 + o) * 2048 + t;
        out[idx] = acc[mi][ni][r] * sc + add + (float)x2ct[idx];
      }
    }
}

extern "C" void kernel_launch(void* const* d_in, const int* in_sizes, int n_in,
                              void* d_out, int out_size, void* d_ws, size_t ws_size,
                              hipStream_t stream) {
  const float* x    = (const float*)d_in[0];
  const float* tcw1 = (const float*)d_in[1];
  const float* tcw2 = (const float*)d_in[2];
  const float* zw   = (const float*)d_in[3];
  const float* zb   = (const float*)d_in[4];
  const float* gw   = (const float*)d_in[5];
  const float* gb   = (const float*)d_in[6];
  const float* thw  = (const float*)d_in[7];
  const float* thb  = (const float*)d_in[8];
  const float* phw  = (const float*)d_in[9];
  const float* phb  = (const float*)d_in[10];
  const float* Ww   = (const float*)d_in[11];
  const float* Wb   = (const float*)d_in[12];
  const float* bng  = (const float*)d_in[13];
  const float* bnb  = (const float*)d_in[14];
  const float* bnm  = (const float*)d_in[15];
  const float* bnv  = (const float*)d_in[16];

  char* Wp = (char*)d_ws;
  _Float16* xpe = (_Float16*)(Wp);                  // [b][t][c] f16      16,777,216 B
  _Float16* Mh  = (_Float16*)(Wp + 16777216);       // [5][o][c] f16       2,621,440
  _Float16* x2h = (_Float16*)(Wp + 19398656);       // [b][t][c] f16      16,777,216
  _Float16* x2c = (_Float16*)(Wp + 36175872);       // [b][c][t] f16      16,777,216
  _Float16* tht = (_Float16*)(Wp + 69730304);       // [b][t][d] f16       8,388,608
  _Float16* pht = (_Float16*)(Wp + 78118912);       // [b][t][d] f16       8,388,608
  _Float16* gv  = (_Float16*)(Wp + 86507520);       // [b][d][t] f16       8,388,608
  _Float16* wc  = (_Float16*)(Wp + 103284736);      // 4 x 131072 f16      1,048,576
  _Float16* wth = wc, *wph = wc + 131072, *wg = wc + 262144, *wW = wc + 393216;
  _Float16* zh  = (_Float16*)(Wp + 36175872);                // aliases x2c (dead until k_conv)
  _Float16* wt  = (_Float16*)(Wp + 36175872 + 1572864);
  // attention split scratch aliases xpe/Mh (dead after k_gtp)
  _Float16* yp  = (_Float16*)(Wp);                  // 2x8x2048x256 f16   16,777,216 B
  float*    mlm = (float*)   (Wp + 16777216);       // 2x8x2048 f32          131,072
  float*    mll = (float*)   (Wp + 16908288);       // 2x8x2048 f32          131,072

  k_prep  <<<5504, 256, 0, stream>>>(thw, phw, gw, Ww, zw, tcw1, tcw2, wc, zh, wt);
  k_merge <<<dim3(8, 8, 5), 256, 0, stream>>>(zh, wt, zw, Mh);
  k_pe_t  <<<dim3(64, 16, 8), 256, 0, stream>>>(x, xpe);
  k_conv  <<<1024, 256, 0, stream>>>(Mh, xpe, zb, x2c, x2h);
  k_gtp   <<<768, 256, 0, stream>>>(x2h, wth, wph, wg, thb, phb, gb, tht, pht, gv);
  k_attn  <<<256, 512, 0, stream>>>(tht, pht, gv, yp, mlm, mll);
  k_final <<<512, 256, 0, stream>>>(wW, yp, mlm, mll, Wb, bng, bnb, bnm, bnv, x2c, (float*)d_out);
}

// Round 17
// 202.501 us; speedup vs baseline: 1.0338x; 1.0338x over previous
//
#include <hip/hip_runtime.h>
#include <stdint.h>

typedef _Float16 h8v __attribute__((ext_vector_type(8)));
typedef float f4v __attribute__((ext_vector_type(4)));

#define MFMA(a,b,c) __builtin_amdgcn_mfma_f32_16x16x32_f16((a),(b),(c),0,0,0)
#define NSPLIT 2

__device__ __forceinline__ _Float16 f2h(float f) { return (_Float16)f; }

// swizzled byte offset: row pitch 64B, 4 chunks of 16B, XOR on (row>>1)&3
__device__ __forceinline__ int swb(int row, int chunk) {
  return row * 64 + (((chunk) ^ ((row >> 1) & 3)) << 4);
}

// P-LDS swizzle (attn)
__device__ __forceinline__ int pswb(int q, int sxb) {
  return q * 128 + (sxb ^ (((q >> 2) & 3) << 5));
}

// async global->LDS, 16B per lane; LDS dest = base + lane*16 (wave-uniform base)
__device__ __forceinline__ void gload16(const void* g, void* l) {
  __builtin_amdgcn_global_load_lds((const __attribute__((address_space(1))) void*)g,
                                   (__attribute__((address_space(3))) void*)l, 16, 0, 0);
}

// ---------------- K1: PE add + transpose:  xpe_t[b][t][c] = f16(x[b][c][t] + pe(t,c))
__global__ __launch_bounds__(256) void k_pe_t(const float* __restrict__ x, _Float16* __restrict__ xpe) {
  __shared__ float tile[32][33];
  int b = blockIdx.z;
  int t0 = blockIdx.x * 32, c0 = blockIdx.y * 32;
  int tid = threadIdx.x;
  int col = tid & 31, rowq = tid >> 5;
#pragma unroll
  for (int i = 0; i < 4; ++i) {
    int c = c0 + rowq + i * 8;
    int t = t0 + col;
    int j2 = c & ~1;
    float dv = expf(-0.01798894603885192f * (float)j2);  // ln(1e4)/512
    float ang = (float)t * dv;
    float pe = (c & 1) ? cosf(ang) : sinf(ang);
    tile[rowq + i * 8][col] = x[((size_t)b * 512 + c) * 2048 + t] + pe;
  }
  __syncthreads();
#pragma unroll
  for (int i = 0; i < 4; ++i) {
    int t = t0 + rowq + i * 8;
    int c = c0 + col;
    xpe[((size_t)b * 2048 + t) * 512 + c] = f2h(tile[col][rowq + i * 8]);
  }
}

// ---------------- K2: fused prep — proj-weight casts, z_w cast, tconv weight transpose
__global__ __launch_bounds__(256) void k_prep(const float* __restrict__ thw, const float* __restrict__ phw,
                                              const float* __restrict__ gw,  const float* __restrict__ Ww,
                                              const float* __restrict__ zw,
                                              const float* __restrict__ w1, const float* __restrict__ w2,
                                              _Float16* __restrict__ wc, _Float16* __restrict__ zh,
                                              _Float16* __restrict__ wt) {
  int task = blockIdx.x;
  int tid = threadIdx.x;
  if (task < 2048) {
    int w = task >> 9;
    const float* s = (w == 0) ? thw : (w == 1) ? phw : (w == 2) ? gw : Ww;
    int i = (task & 511) * 256 + tid;
    wc[(size_t)w * 131072 + i] = f2h(s[i]);
  } else if (task < 5120) {
    int i = (task - 2048) * 256 + tid;
    zh[i] = f2h(zw[i]);
  } else {
    int wb = task - 5120;
    int z = wb >> 6;
    const float* src = (z < 3) ? w1 : w2;
    int k = (z < 3) ? z : z - 3;
    __shared__ _Float16 tile[64][65];
    int m0 = ((wb & 63) >> 3) * 64, c0 = (wb & 7) * 64;
    int tc = tid & 63, tm = tid >> 6;
#pragma unroll
    for (int i = 0; i < 16; ++i) {
      int m = m0 + tm + i * 4;
      tile[tm + i * 4][tc] = f2h(src[(size_t)m * 1536 + (size_t)k * 512 + c0 + tc]);
    }
    __syncthreads();
#pragma unroll
    for (int i = 0; i < 16; ++i) {
      int c = c0 + tm + i * 4;
      wt[((size_t)z * 512 + c) * 512 + m0 + tc] = tile[tc][tm + i * 4];
    }
  }
}

// ---------------- K3: merge conv weights through z (f16 MFMA)
__global__ __launch_bounds__(256) void k_merge(const _Float16* __restrict__ zh,
                                               const _Float16* __restrict__ wt,
                                               const float* __restrict__ zwf,
                                               _Float16* __restrict__ M) {
  int s = blockIdx.z;
  int wid = threadIdx.x >> 6, lane = threadIdx.x & 63;
  int o0 = blockIdx.y * 64 + (wid >> 1) * 32;
  int c0 = blockIdx.x * 64 + (wid & 1) * 32;
  int row16 = lane & 15, kg = lane >> 4, koff = kg * 8;
  f4v acc[2][2];
#pragma unroll
  for (int mi = 0; mi < 2; ++mi)
#pragma unroll
    for (int ni = 0; ni < 2; ++ni) acc[mi][ni] = (f4v){0.f, 0.f, 0.f, 0.f};

  int np = (s == 2) ? 2 : 1;
  for (int p = 0; p < np; ++p) {
    int seg, wi;
    if (s == 0)      { seg = 1024; wi = 3; }
    else if (s == 1) { seg = 512;  wi = 0; }
    else if (s == 3) { seg = 512;  wi = 2; }
    else if (s == 4) { seg = 1024; wi = 5; }
    else             { seg = (p == 0) ? 512 : 1024; wi = (p == 0) ? 1 : 4; }
    const _Float16* A = zh + seg;
    const _Float16* B = wt + (size_t)wi * 512 * 512;
    for (int k0 = 0; k0 < 512; k0 += 32) {
      h8v a[2], bv[2];
#pragma unroll
      for (int i = 0; i < 2; ++i)
        a[i] = *(const h8v*)(A + (size_t)(o0 + i * 16 + row16) * 1536 + k0 + koff);
#pragma unroll
      for (int i = 0; i < 2; ++i)
        bv[i] = *(const h8v*)(B + (size_t)(c0 + i * 16 + row16) * 512 + k0 + koff);
#pragma unroll
      for (int mi = 0; mi < 2; ++mi)
#pragma unroll
        for (int ni = 0; ni < 2; ++ni)
          acc[mi][ni] = MFMA(a[mi], bv[ni], acc[mi][ni]);
    }
  }
  _Float16* dst = M + (size_t)s * 512 * 512;
#pragma unroll
  for (int mi = 0; mi < 2; ++mi)
#pragma unroll
    for (int r = 0; r < 4; ++r) {
      int o = o0 + mi * 16 + kg * 4 + r;
#pragma unroll
      for (int ni = 0; ni < 2; ++ni) {
        int c = c0 + ni * 16 + row16;
        float v = acc[mi][ni][r];
        if (s == 2) v += zwf[(size_t)o * 1536 + c];
        dst[(size_t)o * 512 + c] = f2h(v);
      }
    }
}

// ---------------- shared 128x128 TN GEMM, BOTH operands staged via global_load_lds
__device__ __forceinline__ void gemm128_glds(const _Float16* __restrict__ L, int ldl,
                                             const _Float16* __restrict__ R, int ldr,
                                             int K, int tid, char* lsA, char* lsB,
                                             f4v acc[4][4]) {
  int wid = tid >> 6, lane = tid & 63;
  int wm = (wid >> 1) * 64, wn = (wid & 1) * 64;
  int row16 = lane & 15, kg = lane >> 4;
  int j0 = tid, j1 = tid + 256;
  int r0 = j0 >> 2, c0 = (j0 & 3) ^ ((j0 >> 3) & 3);
  int r1 = j1 >> 2, c1 = (j1 & 3) ^ ((j1 >> 3) & 3);
  const _Float16* La0 = L + (size_t)r0 * ldl + c0 * 8;
  const _Float16* La1 = L + (size_t)r1 * ldl + c1 * 8;
  const _Float16* Rb0 = R + (size_t)r0 * ldr + c0 * 8;
  const _Float16* Rb1 = R + (size_t)r1 * ldr + c1 * 8;
  char* dA0 = lsA + wid * 1024;
  char* dA1 = lsA + 4096 + wid * 1024;
  char* dB0 = lsB + wid * 1024;
  char* dB1 = lsB + 4096 + wid * 1024;

  gload16(La0, dA0); gload16(La1, dA1);
  gload16(Rb0, dB0); gload16(Rb1, dB1);
  __syncthreads();

  int nk = K >> 5;
  for (int kc = 0; kc < nk; ++kc) {
    char* ca = lsA + (kc & 1) * 8192;
    char* cb = lsB + (kc & 1) * 8192;
    if (kc < nk - 1) {
      int k1 = (kc + 1) << 5;
      int off = ((kc + 1) & 1) * 8192;
      gload16(La0 + k1, dA0 + off); gload16(La1 + k1, dA1 + off);
      gload16(Rb0 + k1, dB0 + off); gload16(Rb1 + k1, dB1 + off);
    }
    h8v a[4], bv[4];
#pragma unroll
    for (int i = 0; i < 4; ++i)
      a[i] = *(const h8v*)(ca + swb(wm + i * 16 + row16, kg));
#pragma unroll
    for (int i = 0; i < 4; ++i)
      bv[i] = *(const h8v*)(cb + swb(wn + i * 16 + row16, kg));
#pragma unroll
    for (int mi = 0; mi < 4; ++mi)
#pragma unroll
      for (int ni = 0; ni < 4; ++ni)
        acc[mi][ni] = MFMA(a[mi], bv[ni], acc[mi][ni]);
    __syncthreads();
  }
}

// ---------------- K4: conv GEMM  x2[o][t] = sum_s M_s[o][:]·xpe[t+s-2][:] + zb
// A (merged weights) staged via global_load_lds; B (xpe, halo) reg-staged
__global__ __launch_bounds__(256, 2) void k_conv(const _Float16* __restrict__ Mh,
                                                 const _Float16* __restrict__ xpe,
                                                 const float* __restrict__ zb,
                                                 _Float16* __restrict__ x2ct,
                                                 _Float16* __restrict__ x2h) {
  int b = blockIdx.z;
  int o0 = blockIdx.y * 64, t0 = blockIdx.x * 128;
  int tid = threadIdx.x;
  int wid = tid >> 6, lane = tid & 63;
  int wm = (wid >> 1) * 32, wn = (wid & 1) * 64;
  int row16 = lane & 15, kg = lane >> 4;
  __shared__ __align__(16) char asm2[2][320 * 64];
  __shared__ __align__(16) char bsm[2][132 * 64];
  const _Float16* Xb = xpe + (size_t)b * 2048 * 512;
  const h8v zerov = {0, 0, 0, 0, 0, 0, 0, 0};

  f4v acc[2][4];
#pragma unroll
  for (int mi = 0; mi < 2; ++mi)
#pragma unroll
    for (int ni = 0; ni < 4; ++ni) acc[mi][ni] = (f4v){0.f, 0.f, 0.f, 0.f};

  const _Float16* Asrc[5];
#pragma unroll
  for (int p = 0; p < 5; ++p) {
    int j = tid + 256 * p;
    int row = j >> 2, c = (j & 3) ^ ((j >> 3) & 3);
    Asrc[p] = Mh + (size_t)(row >> 6) * 262144 + (size_t)(o0 + (row & 63)) * 512 + c * 8;
  }
  int achk = tid & 3;
  int br0 = tid >> 2, br1 = (tid + 256) >> 2, br2 = (tid + 512) >> 2;
  int tg0 = t0 + br0 - 2, tg1 = t0 + br1 - 2, tg2 = t0 + br2 - 2;
  bool v0 = (tg0 >= 0 && tg0 < 2048);
  bool v1 = (tg1 >= 0 && tg1 < 2048);
  bool v2 = (tid < 16) && (tg2 >= 0 && tg2 < 2048);
  h8v s0, s1, s2;

#pragma unroll
  for (int p = 0; p < 5; ++p)
    gload16(Asrc[p], (char*)asm2[0] + p * 4096 + wid * 1024);
  s0 = v0 ? *(const h8v*)(Xb + (size_t)tg0 * 512 + achk * 8) : zerov;
  s1 = v1 ? *(const h8v*)(Xb + (size_t)tg1 * 512 + achk * 8) : zerov;
  s2 = v2 ? *(const h8v*)(Xb + (size_t)tg2 * 512 + achk * 8) : zerov;
  *(h8v*)(&bsm[0][swb(br0, achk)]) = s0;
  *(h8v*)(&bsm[0][swb(br1, achk)]) = s1;
  if (tid < 16) *(h8v*)(&bsm[0][swb(br2, achk)]) = s2;
  __syncthreads();

  for (int kc = 0; kc < 16; ++kc) {
    char* ca = asm2[kc & 1];
    char* cb = bsm[kc & 1];
    bool pf = (kc < 15);
    if (pf) {
      int k1 = (kc + 1) * 32;
      char* nbase = (char*)asm2[(kc & 1) ^ 1];
#pragma unroll
      for (int p = 0; p < 5; ++p)
        gload16(Asrc[p] + k1, nbase + p * 4096 + wid * 1024);
      s0 = v0 ? *(const h8v*)(Xb + (size_t)tg0 * 512 + k1 + achk * 8) : zerov;
      s1 = v1 ? *(const h8v*)(Xb + (size_t)tg1 * 512 + k1 + achk * 8) : zerov;
      s2 = v2 ? *(const h8v*)(Xb + (size_t)tg2 * 512 + k1 + achk * 8) : zerov;
    }
#pragma unroll
    for (int s = 0; s < 5; ++s) {
      h8v a[2];
#pragma unroll
      for (int i = 0; i < 2; ++i)
        a[i] = *(const h8v*)(ca + swb(s * 64 + wm + i * 16 + row16, kg));
#pragma unroll
      for (int ni = 0; ni < 4; ++ni) {
        int rr = wn + ni * 16 + row16 + s;
        h8v bv = *(const h8v*)(cb + swb(rr, kg));
#pragma unroll
        for (int mi = 0; mi < 2; ++mi)
          acc[mi][ni] = MFMA(a[mi], bv, acc[mi][ni]);
      }
    }
    if (pf) {
      char* nb = bsm[(kc & 1) ^ 1];
      *(h8v*)(&nb[swb(br0, achk)]) = s0;
      *(h8v*)(&nb[swb(br1, achk)]) = s1;
      if (tid < 16) *(h8v*)(&nb[swb(br2, achk)]) = s2;
    }
    __syncthreads();
  }

#pragma unroll
  for (int mi = 0; mi < 2; ++mi)
#pragma unroll
    for (int r = 0; r < 4; ++r) {
      int o = o0 + wm + mi * 16 + kg * 4 + r;
      float bias = zb[o];
#pragma unroll
      for (int ni = 0; ni < 4; ++ni) {
        int t = t0 + wn + ni * 16 + row16;
        float v = acc[mi][ni][r] + bias;
        x2ct[((size_t)b * 512 + o) * 2048 + t] = f2h(v);
        x2h[((size_t)b * 2048 + t) * 512 + o] = f2h(v);
      }
    }
}

// ---------------- K5: g/theta/phi projections (gload_lds GEMM core)
__global__ __launch_bounds__(256, 3) void k_gtp(const _Float16* __restrict__ x2h,
                                                const _Float16* __restrict__ wth, const _Float16* __restrict__ wph,
                                                const _Float16* __restrict__ wg,
                                                const float* __restrict__ thb, const float* __restrict__ phb,
                                                const float* __restrict__ gb,
                                                _Float16* __restrict__ tht, _Float16* __restrict__ pht,
                                                _Float16* __restrict__ gv) {
  int b = blockIdx.z;
  int proj = blockIdx.y >> 1, dtile = blockIdx.y & 1;
  int tid = threadIdx.x;
  int wid = tid >> 6, lane = tid & 63;
  int wm = (wid >> 1) * 64, wn = (wid & 1) * 64;
  int row16 = lane & 15, kg = lane >> 4;
  __shared__ __align__(16) char lA[2][8192];
  __shared__ __align__(16) char lB[2][8192];
  const _Float16* X = x2h + (size_t)b * 2048 * 512;
  f4v acc[4][4];
#pragma unroll
  for (int mi = 0; mi < 4; ++mi)
#pragma unroll
    for (int ni = 0; ni < 4; ++ni) acc[mi][ni] = (f4v){0.f, 0.f, 0.f, 0.f};

  if (proj < 2) {
    const _Float16* W = (proj == 0) ? wth : wph;
    const float* bias = (proj == 0) ? thb : phb;
    _Float16* out = (proj == 0) ? tht : pht;
    int m0 = blockIdx.x * 128, n0 = dtile * 128;
    gemm128_glds(X + (size_t)m0 * 512, 512, W + (size_t)n0 * 512, 512, 512, tid, lA[0], lB[0], acc);
#pragma unroll
    for (int mi = 0; mi < 4; ++mi)
#pragma unroll
      for (int r = 0; r < 4; ++r) {
        int t = m0 + wm + mi * 16 + kg * 4 + r;
#pragma unroll
        for (int ni = 0; ni < 4; ++ni) {
          int d = n0 + wn + ni * 16 + row16;
          out[((size_t)b * 2048 + t) * 256 + d] = f2h(acc[mi][ni][r] + bias[d]);
        }
      }
  } else {
    int m0 = dtile * 128, n0 = blockIdx.x * 128;
    gemm128_glds(wg + (size_t)m0 * 512, 512, X + (size_t)n0 * 512, 512, 512, tid, lA[0], lB[0], acc);
#pragma unroll
    for (int mi = 0; mi < 4; ++mi)
#pragma unroll
      for (int r = 0; r < 4; ++r) {
        int d = m0 + wm + mi * 16 + kg * 4 + r;
        float bias = gb[d];
#pragma unroll
        for (int ni = 0; ni < 4; ++ni) {
          int t = n0 + wn + ni * 16 + row16;
          gv[((size_t)b * 256 + d) * 2048 + t] = f2h(acc[mi][ni][r] + bias);
        }
      }
  }
}

// ---------------- K6: flash attention (512 thr, single 64KB K/V buffer, register
// prefetch, defer-max)
__global__ __launch_bounds__(512) void k_attn(const _Float16* __restrict__ tht,
                                              const _Float16* __restrict__ pht,
                                              const _Float16* __restrict__ gv,
                                              _Float16* __restrict__ yp,
                                              float* __restrict__ mlm, float* __restrict__ mll) {
  int b = blockIdx.z, sp = blockIdx.y;
  int tid = threadIdx.x;
  int wid = tid >> 6, lane = tid & 63;
  int q0 = blockIdx.x * 128 + wid * 16;
  int row16 = lane & 15, kg = lane >> 4, koff = kg * 8;
  int rswz = row16 & 7;

  __shared__ __align__(16) _Float16 kvbuf[32768];
  __shared__ __align__(16) _Float16 p_lds[8][1024];
  char* pw = (char*)&p_lds[wid][0];
  char* cb = (char*)&kvbuf[0];

  const _Float16* thb = tht + (size_t)b * 2048 * 256;
  const _Float16* phb = pht + (size_t)b * 2048 * 256;
  const _Float16* gvb = gv + (size_t)b * 256 * 2048;

  h8v qf[8];
#pragma unroll
  for (int ks = 0; ks < 8; ++ks)
    qf[ks] = *(const h8v*)(thb + (size_t)(q0 + row16) * 256 + ks * 32 + koff);

  float m_i[4], l_i[4];
#pragma unroll
  for (int r = 0; r < 4; ++r) { m_i[r] = -3e38f; l_i[r] = 0.f; }
  f4v yacc[16];
#pragma unroll
  for (int ni = 0; ni < 16; ++ni) yacc[ni] = (f4v){0.f, 0.f, 0.f, 0.f};

  {
    int k0 = sp * 1024;
#pragma unroll
    for (int j = 0; j < 4; ++j) {
      int idx = tid + 512 * j;
      h8v kv = *(const h8v*)(phb + (size_t)(k0 + (idx >> 5)) * 256 + (idx & 31) * 8);
      h8v vv = *(const h8v*)(gvb + (size_t)(idx >> 3) * 2048 + k0 + (idx & 7) * 8);
      *(h8v*)(cb + (idx >> 5) * 512 + (((idx & 31) ^ ((idx >> 5) & 7)) << 4)) = kv;
      *(h8v*)(cb + 32768 + (idx >> 3) * 128 + (((idx & 7) ^ ((idx >> 3) & 7)) << 4)) = vv;
    }
  }
  __syncthreads();

  for (int t = 0; t < 16; ++t) {
    int k0 = sp * 1024 + t * 64;

    h8v kreg[4], vreg[4];
    bool pf = (t < 15);
    if (pf) {
      int k1 = k0 + 64;
#pragma unroll
      for (int j = 0; j < 4; ++j) {
        int idx = tid + 512 * j;
        kreg[j] = *(const h8v*)(phb + (size_t)(k1 + (idx >> 5)) * 256 + (idx & 31) * 8);
        vreg[j] = *(const h8v*)(gvb + (size_t)(idx >> 3) * 2048 + k1 + (idx & 7) * 8);
      }
    }

    f4v sacc[4];
#pragma unroll
    for (int ni = 0; ni < 4; ++ni) sacc[ni] = (f4v){0.f, 0.f, 0.f, 0.f};
#pragma unroll
    for (int ks = 0; ks < 8; ++ks) {
#pragma unroll
      for (int ni = 0; ni < 4; ++ni) {
        int krow = ni * 16 + row16;
        h8v kf = *(const h8v*)(cb + krow * 512 + ((((ks << 2) | kg) ^ rswz) << 4));
        sacc[ni] = MFMA(qf[ks], kf, sacc[ni]);
      }
    }
    float al[4] = {1.f, 1.f, 1.f, 1.f};
    float rmv[4];
    float nd = 0.f;
#pragma unroll
    for (int r = 0; r < 4; ++r) {
      float rm = fmaxf(fmaxf(sacc[0][r], sacc[1][r]), fmaxf(sacc[2][r], sacc[3][r]));
#pragma unroll
      for (int m = 1; m <= 8; m <<= 1) rm = fmaxf(rm, __shfl_xor(rm, m, 64));
      rmv[r] = rm;
      if (rm > m_i[r] + 8.f) nd = 1.f;
    }
    if (__any(nd != 0.f)) {
#pragma unroll
      for (int r = 0; r < 4; ++r) {
        float mn = fmaxf(m_i[r], rmv[r]);
        al[r] = __expf(m_i[r] - mn);
        m_i[r] = mn;
      }
#pragma unroll
      for (int ni = 0; ni < 16; ++ni)
#pragma unroll
        for (int r = 0; r < 4; ++r) yacc[ni][r] *= al[r];
    }
#pragma unroll
    for (int r = 0; r < 4; ++r) {
      float rs = 0.f;
#pragma unroll
      for (int ni = 0; ni < 4; ++ni) {
        float p = __expf(sacc[ni][r] - m_i[r]);
        sacc[ni][r] = p;
        rs += p;
      }
#pragma unroll
      for (int m = 1; m <= 8; m <<= 1) rs += __shfl_xor(rs, m, 64);
      l_i[r] = l_i[r] * al[r] + rs;
    }
#pragma unroll
    for (int r = 0; r < 4; ++r) {
      int q = kg * 4 + r;
#pragma unroll
      for (int ni = 0; ni < 4; ++ni) {
        int sx = ni * 16 + row16;
        *(_Float16*)(pw + pswb(q, sx * 2)) = f2h(sacc[ni][r]);
      }
    }
#pragma unroll
    for (int ks2 = 0; ks2 < 2; ++ks2) {
      h8v pa = *(const h8v*)(pw + pswb(row16, (ks2 * 32 + koff) * 2));
#pragma unroll
      for (int ni = 0; ni < 16; ++ni) {
        int d = ni * 16 + row16;
        h8v vb = *(const h8v*)(cb + 32768 + d * 128 + ((((ks2 << 2) | kg) ^ rswz) << 4));
        yacc[ni] = MFMA(pa, vb, yacc[ni]);
      }
    }
    if (pf) {
      __syncthreads();
#pragma unroll
      for (int j = 0; j < 4; ++j) {
        int idx = tid + 512 * j;
        *(h8v*)(cb + (idx >> 5) * 512 + (((idx & 31) ^ ((idx >> 5) & 7)) << 4)) = kreg[j];
        *(h8v*)(cb + 32768 + (idx >> 3) * 128 + (((idx & 7) ^ ((idx >> 3) & 7)) << 4)) = vreg[j];
      }
      __syncthreads();
    }
  }

  _Float16* yb = yp + (size_t)(sp * 8 + b) * 2048 * 256;
  float* mm = mlm + (size_t)(sp * 8 + b) * 2048;
  float* ml = mll + (size_t)(sp * 8 + b) * 2048;
#pragma unroll
  for (int r = 0; r < 4; ++r) {
    int q = q0 + kg * 4 + r;
#pragma unroll
    for (int ni = 0; ni < 16; ++ni)
      yb[(size_t)q * 256 + ni * 16 + row16] = f2h(yacc[ni][r]);
    if (row16 == 0) { mm[q] = m_i[r]; ml[q] = l_i[r]; }
  }
}

// ---------------- K7: out = BN(W@y + Wb) + x2, combine fused; A via gload_lds
__global__ __launch_bounds__(256, 3) void k_final(const _Float16* __restrict__ Wh,
                                                  const _Float16* __restrict__ yp,
                                                  const float* __restrict__ mlm, const float* __restrict__ mll,
                                                  const float* __restrict__ Wb,
                                                  const float* __restrict__ bng, const float* __restrict__ bnb,
                                                  const float* __restrict__ bnm, const float* __restrict__ bnv,
                                                  const _Float16* __restrict__ x2ct, float* __restrict__ out) {
  int b = blockIdx.z;
  int o0 = blockIdx.y * 128, t0 = blockIdx.x * 128;
  int tid = threadIdx.x;
  int wid = tid >> 6, lane = tid & 63;
  int wm = (wid >> 1) * 64, wn = (wid & 1) * 64;
  int row16 = lane & 15, kg = lane >> 4;
  __shared__ __align__(16) char lA[2][8192];
  __shared__ __align__(16) char lB[2][8192];
  f4v acc[4][4];
#pragma unroll
  for (int mi = 0; mi < 4; ++mi)
#pragma unroll
    for (int ni = 0; ni < 4; ++ni) acc[mi][ni] = (f4v){0.f, 0.f, 0.f, 0.f};

  const _Float16* L = Wh + (size_t)o0 * 256;
  const _Float16* Y0 = yp + ((size_t)b * 2048 + t0) * 256;
  const _Float16* Y1 = yp + ((size_t)(8 + b) * 2048 + t0) * 256;
  int ar0 = tid >> 2, ar1 = ar0 + 64, ach = tid & 3;
  int j0 = tid, j1 = tid + 256;
  int gr0 = j0 >> 2, gc0 = (j0 & 3) ^ ((j0 >> 3) & 3);
  int gr1 = j1 >> 2, gc1 = (j1 & 3) ^ ((j1 >> 3) & 3);
  const _Float16* La0 = L + (size_t)gr0 * 256 + gc0 * 8;
  const _Float16* La1 = L + (size_t)gr1 * 256 + gc1 * 8;
  char* dA0 = lA[0] + wid * 1024;
  char* dA1 = lA[0] + 4096 + wid * 1024;

  float w0a, w1a, w0b, w1b;
  {
    int qa = t0 + ar0, qb = t0 + ar1;
    float mA0 = mlm[(size_t)b * 2048 + qa], mA1 = mlm[(size_t)(8 + b) * 2048 + qa];
    float Ma = fmaxf(mA0, mA1);
    float e0 = __expf(mA0 - Ma), e1 = __expf(mA1 - Ma);
    float La = e0 * mll[(size_t)b * 2048 + qa] + e1 * mll[(size_t)(8 + b) * 2048 + qa];
    float ia = 1.f / La;
    w0a = e0 * ia; w1a = e1 * ia;
    float mB0 = mlm[(size_t)b * 2048 + qb], mB1 = mlm[(size_t)(8 + b) * 2048 + qb];
    float Mb = fmaxf(mB0, mB1);
    float f0 = __expf(mB0 - Mb), f1 = __expf(mB1 - Mb);
    float Lb = f0 * mll[(size_t)b * 2048 + qb] + f1 * mll[(size_t)(8 + b) * 2048 + qb];
    float ib = 1.f / Lb;
    w0b = f0 * ib; w1b = f1 * ib;
  }

  h8v pb0, pb1;
  auto comb = [&](const _Float16* y0, const _Float16* y1, float w0, float w1) -> h8v {
    h8v u = *(const h8v*)y0, v = *(const h8v*)y1, o;
#pragma unroll
    for (int j = 0; j < 8; ++j) o[j] = f2h(w0 * (float)u[j] + w1 * (float)v[j]);
    return o;
  };

  gload16(La0, dA0); gload16(La1, dA1);
  pb0 = comb(Y0 + (size_t)ar0 * 256 + ach * 8, Y1 + (size_t)ar0 * 256 + ach * 8, w0a, w1a);
  pb1 = comb(Y0 + (size_t)ar1 * 256 + ach * 8, Y1 + (size_t)ar1 * 256 + ach * 8, w0b, w1b);
  *(h8v*)(lB[0] + swb(ar0, ach)) = pb0;
  *(h8v*)(lB[0] + swb(ar1, ach)) = pb1;
  __syncthreads();

  for (int kc = 0; kc < 8; ++kc) {
    char* ca = lA[kc & 1];
    char* cbp = lB[kc & 1];
    bool pf = (kc < 7);
    if (pf) {
      int k1 = (kc + 1) << 5;
      int off = ((kc + 1) & 1) * 8192;
      gload16(La0 + k1, dA0 + off); gload16(La1 + k1, dA1 + off);
      pb0 = comb(Y0 + (size_t)ar0 * 256 + k1 + ach * 8, Y1 + (size_t)ar0 * 256 + k1 + ach * 8, w0a, w1a);
      pb1 = comb(Y0 + (size_t)ar1 * 256 + k1 + ach * 8, Y1 + (size_t)ar1 * 256 + k1 + ach * 8, w0b, w1b);
    }
    h8v a[4], bv[4];
#pragma unroll
    for (int i = 0; i < 4; ++i)
      a[i] = *(const h8v*)(ca + swb(wm + i * 16 + row16, kg));
#pragma unroll
    for (int i = 0; i < 4; ++i)
      bv[i] = *(const h8v*)(cbp + swb(wn + i * 16 + row16, kg));
#pragma unroll
    for (int mi = 0; mi < 4; ++mi)
#pragma unroll
      for (int ni = 0; ni < 4; ++ni)
        acc[mi][ni] = MFMA(a[mi], bv[ni], acc[mi][ni]);
    if (pf) {
      char* nb = lB[(kc & 1) ^ 1];
      *(h8v*)(nb + swb(ar0, ach)) = pb0;
      *(h8v*)(nb + swb(ar1, ach)) = pb1;
    }
    __syncthreads();
  }

#pragma unroll
  for (int mi = 0; mi < 4; ++mi)
#pragma unroll
    for (int r = 0; r < 4; ++r) {
      int o = o0 + wm + mi * 16 + kg * 4 + r;
      float sc = bng[o] * rsqrtf(bnv[o] + 1e-5f);
      float add = (Wb[o] - bnm[o]) * sc + bnb[o];
#pragma unroll
      for (int ni = 0; ni < 4; ++ni) {
        int t = t0 + wn + ni * 16 + row16;
        size_t idx = ((size_t)b * 512 + o) * 2048 + t;
        out[idx] = acc[mi][ni][r] * sc + add + (float)x2ct[idx];
      }
    }
}

extern "C" void kernel_launch(void* const* d_in, const int* in_sizes, int n_in,
                              void* d_out, int out_size, void* d_ws, size_t ws_size,
                              hipStream_t stream) {
  const float* x    = (const float*)d_in[0];
  const float* tcw1 = (const float*)d_in[1];
  const float* tcw2 = (const float*)d_in[2];
  const float* zw   = (const float*)d_in[3];
  const float* zb   = (const float*)d_in[4];
  const float* gw   = (const float*)d_in[5];
  const float* gb   = (const float*)d_in[6];
  const float* thw  = (const float*)d_in[7];
  const float* thb  = (const float*)d_in[8];
  const float* phw  = (const float*)d_in[9];
  const float* phb  = (const float*)d_in[10];
  const float* Ww   = (const float*)d_in[11];
  const float* Wb   = (const float*)d_in[12];
  const float* bng  = (const float*)d_in[13];
  const float* bnb  = (const float*)d_in[14];
  const float* bnm  = (const float*)d_in[15];
  const float* bnv  = (const float*)d_in[16];

  char* Wp = (char*)d_ws;
  _Float16* xpe = (_Float16*)(Wp);                  // [b][t][c] f16      16,777,216 B
  _Float16* Mh  = (_Float16*)(Wp + 16777216);       // [5][o][c] f16       2,621,440
  _Float16* x2h = (_Float16*)(Wp + 19398656);       // [b][t][c] f16      16,777,216
  _Float16* x2c = (_Float16*)(Wp + 36175872);       // [b][c][t] f16      16,777,216
  _Float16* tht = (_Float16*)(Wp + 69730304);       // [b][t][d] f16       8,388,608
  _Float16* pht = (_Float16*)(Wp + 78118912);       // [b][t][d] f16       8,388,608
  _Float16* gv  = (_Float16*)(Wp + 86507520);       // [b][d][t] f16       8,388,608
  _Float16* wc  = (_Float16*)(Wp + 103284736);      // 4 x 131072 f16      1,048,576
  _Float16* wth = wc, *wph = wc + 131072, *wg = wc + 262144, *wW = wc + 393216;
  _Float16* zh  = (_Float16*)(Wp + 36175872);                // aliases x2c (dead until k_conv)
  _Float16* wt  = (_Float16*)(Wp + 36175872 + 1572864);
  // attention split scratch aliases xpe/Mh (dead after k_gtp)
  _Float16* yp  = (_Float16*)(Wp);                  // 2x8x2048x256 f16   16,777,216 B
  float*    mlm = (float*)   (Wp + 16777216);       // 2x8x2048 f32          131,072
  float*    mll = (float*)   (Wp + 16908288);       // 2x8x2048 f32          131,072

  k_prep  <<<5504, 256, 0, stream>>>(thw, phw, gw, Ww, zw, tcw1, tcw2, wc, zh, wt);
  k_merge <<<dim3(8, 8, 5), 256, 0, stream>>>(zh, wt, zw, Mh);
  k_pe_t  <<<dim3(64, 16, 8), 256, 0, stream>>>(x, xpe);
  k_conv  <<<dim3(16, 8, 8), 256, 0, stream>>>(Mh, xpe, zb, x2c, x2h);
  k_gtp   <<<dim3(16, 6, 8), 256, 0, stream>>>(x2h, wth, wph, wg, thb, phb, gb, tht, pht, gv);
  k_attn  <<<dim3(16, NSPLIT, 8), 512, 0, stream>>>(tht, pht, gv, yp, mlm, mll);
  k_final <<<dim3(16, 4, 8), 256, 0, stream>>>(wW, yp, mlm, mll, Wb, bng, bnb, bnm, bnv, x2c, (float*)d_out);
}

// Round 18
// 197.670 us; speedup vs baseline: 1.0591x; 1.0244x over previous
//
#include <hip/hip_runtime.h>
#include <stdint.h>

typedef _Float16 h8v __attribute__((ext_vector_type(8)));
typedef float f4v __attribute__((ext_vector_type(4)));

#define MFMA(a,b,c) __builtin_amdgcn_mfma_f32_16x16x32_f16((a),(b),(c),0,0,0)
#define NSPLIT 2

__device__ __forceinline__ _Float16 f2h(float f) { return (_Float16)f; }

// swizzled byte offset: row pitch 64B, 4 chunks of 16B, XOR on (row>>1)&3
__device__ __forceinline__ int swb(int row, int chunk) {
  return row * 64 + (((chunk) ^ ((row >> 1) & 3)) << 4);
}

// P-LDS swizzle (attn)
__device__ __forceinline__ int pswb(int q, int sxb) {
  return q * 128 + (sxb ^ (((q >> 2) & 3) << 5));
}

// async global->LDS, 16B per lane; LDS dest = base + lane*16 (wave-uniform base)
__device__ __forceinline__ void gload16(const void* g, void* l) {
  __builtin_amdgcn_global_load_lds((const __attribute__((address_space(1))) void*)g,
                                   (__attribute__((address_space(3))) void*)l, 16, 0, 0);
}

// ---------------- K1: fused prep — proj-weight casts, z_w cast, tconv weight transpose,
// PE-add+transpose (tasks 5504..13695)
__global__ __launch_bounds__(256) void k_prep(const float* __restrict__ thw, const float* __restrict__ phw,
                                              const float* __restrict__ gw,  const float* __restrict__ Ww,
                                              const float* __restrict__ zw,
                                              const float* __restrict__ w1, const float* __restrict__ w2,
                                              const float* __restrict__ x,
                                              _Float16* __restrict__ wc, _Float16* __restrict__ zh,
                                              _Float16* __restrict__ wt, _Float16* __restrict__ xpe) {
  int task = blockIdx.x;
  int tid = threadIdx.x;
  if (task < 2048) {
    int w = task >> 9;
    const float* s = (w == 0) ? thw : (w == 1) ? phw : (w == 2) ? gw : Ww;
    int i = (task & 511) * 256 + tid;
    wc[(size_t)w * 131072 + i] = f2h(s[i]);
  } else if (task < 5120) {
    int i = (task - 2048) * 256 + tid;
    zh[i] = f2h(zw[i]);
  } else if (task < 5504) {
    int wb = task - 5120;
    int z = wb >> 6;
    const float* src = (z < 3) ? w1 : w2;
    int k = (z < 3) ? z : z - 3;
    __shared__ _Float16 tile[64][65];
    int m0 = ((wb & 63) >> 3) * 64, c0 = (wb & 7) * 64;
    int tc = tid & 63, tm = tid >> 6;
#pragma unroll
    for (int i = 0; i < 16; ++i) {
      int m = m0 + tm + i * 4;
      tile[tm + i * 4][tc] = f2h(src[(size_t)m * 1536 + (size_t)k * 512 + c0 + tc]);
    }
    __syncthreads();
#pragma unroll
    for (int i = 0; i < 16; ++i) {
      int c = c0 + tm + i * 4;
      wt[((size_t)z * 512 + c) * 512 + m0 + tc] = tile[tc][tm + i * 4];
    }
  } else {
    // PE add + transpose: xpe[b][t][c] = f16(x[b][c][t] + pe(t,c))
    int wb = task - 5504;                     // 0..8191
    int t0 = (wb & 63) * 32;
    int c0 = ((wb >> 6) & 15) * 32;
    int b  = wb >> 10;
    __shared__ float tile[32][33];
    int col = tid & 31, rowq = tid >> 5;
#pragma unroll
    for (int i = 0; i < 4; ++i) {
      int c = c0 + rowq + i * 8;
      int t = t0 + col;
      int j2 = c & ~1;
      float dv = expf(-0.01798894603885192f * (float)j2);  // ln(1e4)/512
      float ang = (float)t * dv;
      float pe = (c & 1) ? cosf(ang) : sinf(ang);
      tile[rowq + i * 8][col] = x[((size_t)b * 512 + c) * 2048 + t] + pe;
    }
    __syncthreads();
#pragma unroll
    for (int i = 0; i < 4; ++i) {
      int t = t0 + rowq + i * 8;
      int c = c0 + col;
      xpe[((size_t)b * 2048 + t) * 512 + c] = f2h(tile[col][rowq + i * 8]);
    }
  }
}

// ---------------- K2: merge conv weights through z (f16 MFMA)
__global__ __launch_bounds__(256) void k_merge(const _Float16* __restrict__ zh,
                                               const _Float16* __restrict__ wt,
                                               const float* __restrict__ zwf,
                                               _Float16* __restrict__ M) {
  int s = blockIdx.z;
  int wid = threadIdx.x >> 6, lane = threadIdx.x & 63;
  int o0 = blockIdx.y * 64 + (wid >> 1) * 32;
  int c0 = blockIdx.x * 64 + (wid & 1) * 32;
  int row16 = lane & 15, kg = lane >> 4, koff = kg * 8;
  f4v acc[2][2];
#pragma unroll
  for (int mi = 0; mi < 2; ++mi)
#pragma unroll
    for (int ni = 0; ni < 2; ++ni) acc[mi][ni] = (f4v){0.f, 0.f, 0.f, 0.f};

  int np = (s == 2) ? 2 : 1;
  for (int p = 0; p < np; ++p) {
    int seg, wi;
    if (s == 0)      { seg = 1024; wi = 3; }
    else if (s == 1) { seg = 512;  wi = 0; }
    else if (s == 3) { seg = 512;  wi = 2; }
    else if (s == 4) { seg = 1024; wi = 5; }
    else             { seg = (p == 0) ? 512 : 1024; wi = (p == 0) ? 1 : 4; }
    const _Float16* A = zh + seg;
    const _Float16* B = wt + (size_t)wi * 512 * 512;
    for (int k0 = 0; k0 < 512; k0 += 32) {
      h8v a[2], bv[2];
#pragma unroll
      for (int i = 0; i < 2; ++i)
        a[i] = *(const h8v*)(A + (size_t)(o0 + i * 16 + row16) * 1536 + k0 + koff);
#pragma unroll
      for (int i = 0; i < 2; ++i)
        bv[i] = *(const h8v*)(B + (size_t)(c0 + i * 16 + row16) * 512 + k0 + koff);
#pragma unroll
      for (int mi = 0; mi < 2; ++mi)
#pragma unroll
        for (int ni = 0; ni < 2; ++ni)
          acc[mi][ni] = MFMA(a[mi], bv[ni], acc[mi][ni]);
    }
  }
  _Float16* dst = M + (size_t)s * 512 * 512;
#pragma unroll
  for (int mi = 0; mi < 2; ++mi)
#pragma unroll
    for (int r = 0; r < 4; ++r) {
      int o = o0 + mi * 16 + kg * 4 + r;
#pragma unroll
      for (int ni = 0; ni < 2; ++ni) {
        int c = c0 + ni * 16 + row16;
        float v = acc[mi][ni][r];
        if (s == 2) v += zwf[(size_t)o * 1536 + c];
        dst[(size_t)o * 512 + c] = f2h(v);
      }
    }
}

// ---------------- shared 128x128 TN GEMM, BOTH operands staged via global_load_lds
__device__ __forceinline__ void gemm128_glds(const _Float16* __restrict__ L, int ldl,
                                             const _Float16* __restrict__ R, int ldr,
                                             int K, int tid, char* lsA, char* lsB,
                                             f4v acc[4][4]) {
  int wid = tid >> 6, lane = tid & 63;
  int wm = (wid >> 1) * 64, wn = (wid & 1) * 64;
  int row16 = lane & 15, kg = lane >> 4;
  int j0 = tid, j1 = tid + 256;
  int r0 = j0 >> 2, c0 = (j0 & 3) ^ ((j0 >> 3) & 3);
  int r1 = j1 >> 2, c1 = (j1 & 3) ^ ((j1 >> 3) & 3);
  const _Float16* La0 = L + (size_t)r0 * ldl + c0 * 8;
  const _Float16* La1 = L + (size_t)r1 * ldl + c1 * 8;
  const _Float16* Rb0 = R + (size_t)r0 * ldr + c0 * 8;
  const _Float16* Rb1 = R + (size_t)r1 * ldr + c1 * 8;
  char* dA0 = lsA + wid * 1024;
  char* dA1 = lsA + 4096 + wid * 1024;
  char* dB0 = lsB + wid * 1024;
  char* dB1 = lsB + 4096 + wid * 1024;

  gload16(La0, dA0); gload16(La1, dA1);
  gload16(Rb0, dB0); gload16(Rb1, dB1);
  __syncthreads();

  int nk = K >> 5;
  for (int kc = 0; kc < nk; ++kc) {
    char* ca = lsA + (kc & 1) * 8192;
    char* cb = lsB + (kc & 1) * 8192;
    if (kc < nk - 1) {
      int k1 = (kc + 1) << 5;
      int off = ((kc + 1) & 1) * 8192;
      gload16(La0 + k1, dA0 + off); gload16(La1 + k1, dA1 + off);
      gload16(Rb0 + k1, dB0 + off); gload16(Rb1 + k1, dB1 + off);
    }
    h8v a[4], bv[4];
#pragma unroll
    for (int i = 0; i < 4; ++i)
      a[i] = *(const h8v*)(ca + swb(wm + i * 16 + row16, kg));
#pragma unroll
    for (int i = 0; i < 4; ++i)
      bv[i] = *(const h8v*)(cb + swb(wn + i * 16 + row16, kg));
#pragma unroll
    for (int mi = 0; mi < 4; ++mi)
#pragma unroll
      for (int ni = 0; ni < 4; ++ni)
        acc[mi][ni] = MFMA(a[mi], bv[ni], acc[mi][ni]);
    __syncthreads();
  }
}

// ---------------- K3: conv GEMM  x2[o][t] = sum_s M_s[o][:]·xpe[t+s-2][:] + zb
__global__ __launch_bounds__(256, 2) void k_conv(const _Float16* __restrict__ Mh,
                                                 const _Float16* __restrict__ xpe,
                                                 const float* __restrict__ zb,
                                                 _Float16* __restrict__ x2ct,
                                                 _Float16* __restrict__ x2h) {
  int b = blockIdx.z;
  int o0 = blockIdx.y * 64, t0 = blockIdx.x * 128;
  int tid = threadIdx.x;
  int wid = tid >> 6, lane = tid & 63;
  int wm = (wid >> 1) * 32, wn = (wid & 1) * 64;
  int row16 = lane & 15, kg = lane >> 4;
  __shared__ __align__(16) char asm2[2][320 * 64];
  __shared__ __align__(16) char bsm[2][132 * 64];
  const _Float16* Xb = xpe + (size_t)b * 2048 * 512;
  const h8v zerov = {0, 0, 0, 0, 0, 0, 0, 0};

  f4v acc[2][4];
#pragma unroll
  for (int mi = 0; mi < 2; ++mi)
#pragma unroll
    for (int ni = 0; ni < 4; ++ni) acc[mi][ni] = (f4v){0.f, 0.f, 0.f, 0.f};

  const _Float16* Asrc[5];
#pragma unroll
  for (int p = 0; p < 5; ++p) {
    int j = tid + 256 * p;
    int row = j >> 2, c = (j & 3) ^ ((j >> 3) & 3);
    Asrc[p] = Mh + (size_t)(row >> 6) * 262144 + (size_t)(o0 + (row & 63)) * 512 + c * 8;
  }
  int achk = tid & 3;
  int br0 = tid >> 2, br1 = (tid + 256) >> 2, br2 = (tid + 512) >> 2;
  int tg0 = t0 + br0 - 2, tg1 = t0 + br1 - 2, tg2 = t0 + br2 - 2;
  bool v0 = (tg0 >= 0 && tg0 < 2048);
  bool v1 = (tg1 >= 0 && tg1 < 2048);
  bool v2 = (tid < 16) && (tg2 >= 0 && tg2 < 2048);
  h8v s0, s1, s2;

#pragma unroll
  for (int p = 0; p < 5; ++p)
    gload16(Asrc[p], (char*)asm2[0] + p * 4096 + wid * 1024);
  s0 = v0 ? *(const h8v*)(Xb + (size_t)tg0 * 512 + achk * 8) : zerov;
  s1 = v1 ? *(const h8v*)(Xb + (size_t)tg1 * 512 + achk * 8) : zerov;
  s2 = v2 ? *(const h8v*)(Xb + (size_t)tg2 * 512 + achk * 8) : zerov;
  *(h8v*)(&bsm[0][swb(br0, achk)]) = s0;
  *(h8v*)(&bsm[0][swb(br1, achk)]) = s1;
  if (tid < 16) *(h8v*)(&bsm[0][swb(br2, achk)]) = s2;
  __syncthreads();

  for (int kc = 0; kc < 16; ++kc) {
    char* ca = asm2[kc & 1];
    char* cb = bsm[kc & 1];
    bool pf = (kc < 15);
    if (pf) {
      int k1 = (kc + 1) * 32;
      char* nbase = (char*)asm2[(kc & 1) ^ 1];
#pragma unroll
      for (int p = 0; p < 5; ++p)
        gload16(Asrc[p] + k1, nbase + p * 4096 + wid * 1024);
      s0 = v0 ? *(const h8v*)(Xb + (size_t)tg0 * 512 + k1 + achk * 8) : zerov;
      s1 = v1 ? *(const h8v*)(Xb + (size_t)tg1 * 512 + k1 + achk * 8) : zerov;
      s2 = v2 ? *(const h8v*)(Xb + (size_t)tg2 * 512 + k1 + achk * 8) : zerov;
    }
#pragma unroll
    for (int s = 0; s < 5; ++s) {
      h8v a[2];
#pragma unroll
      for (int i = 0; i < 2; ++i)
        a[i] = *(const h8v*)(ca + swb(s * 64 + wm + i * 16 + row16, kg));
#pragma unroll
      for (int ni = 0; ni < 4; ++ni) {
        int rr = wn + ni * 16 + row16 + s;
        h8v bv = *(const h8v*)(cb + swb(rr, kg));
#pragma unroll
        for (int mi = 0; mi < 2; ++mi)
          acc[mi][ni] = MFMA(a[mi], bv, acc[mi][ni]);
      }
    }
    if (pf) {
      char* nb = bsm[(kc & 1) ^ 1];
      *(h8v*)(&nb[swb(br0, achk)]) = s0;
      *(h8v*)(&nb[swb(br1, achk)]) = s1;
      if (tid < 16) *(h8v*)(&nb[swb(br2, achk)]) = s2;
    }
    __syncthreads();
  }

#pragma unroll
  for (int mi = 0; mi < 2; ++mi)
#pragma unroll
    for (int r = 0; r < 4; ++r) {
      int o = o0 + wm + mi * 16 + kg * 4 + r;
      float bias = zb[o];
#pragma unroll
      for (int ni = 0; ni < 4; ++ni) {
        int t = t0 + wn + ni * 16 + row16;
        float v = acc[mi][ni][r] + bias;
        x2ct[((size_t)b * 512 + o) * 2048 + t] = f2h(v);
        x2h[((size_t)b * 2048 + t) * 512 + o] = f2h(v);
      }
    }
}

// ---------------- K4: g/theta/phi projections (gload_lds GEMM core)
__global__ __launch_bounds__(256, 3) void k_gtp(const _Float16* __restrict__ x2h,
                                                const _Float16* __restrict__ wth, const _Float16* __restrict__ wph,
                                                const _Float16* __restrict__ wg,
                                                const float* __restrict__ thb, const float* __restrict__ phb,
                                                const float* __restrict__ gb,
                                                _Float16* __restrict__ tht, _Float16* __restrict__ pht,
                                                _Float16* __restrict__ gv) {
  int b = blockIdx.z;
  int proj = blockIdx.y >> 1, dtile = blockIdx.y & 1;
  int tid = threadIdx.x;
  int wid = tid >> 6, lane = tid & 63;
  int wm = (wid >> 1) * 64, wn = (wid & 1) * 64;
  int row16 = lane & 15, kg = lane >> 4;
  __shared__ __align__(16) char lA[2][8192];
  __shared__ __align__(16) char lB[2][8192];
  const _Float16* X = x2h + (size_t)b * 2048 * 512;
  f4v acc[4][4];
#pragma unroll
  for (int mi = 0; mi < 4; ++mi)
#pragma unroll
    for (int ni = 0; ni < 4; ++ni) acc[mi][ni] = (f4v){0.f, 0.f, 0.f, 0.f};

  if (proj < 2) {
    const _Float16* W = (proj == 0) ? wth : wph;
    const float* bias = (proj == 0) ? thb : phb;
    _Float16* out = (proj == 0) ? tht : pht;
    int m0 = blockIdx.x * 128, n0 = dtile * 128;
    gemm128_glds(X + (size_t)m0 * 512, 512, W + (size_t)n0 * 512, 512, 512, tid, lA[0], lB[0], acc);
#pragma unroll
    for (int mi = 0; mi < 4; ++mi)
#pragma unroll
      for (int r = 0; r < 4; ++r) {
        int t = m0 + wm + mi * 16 + kg * 4 + r;
#pragma unroll
        for (int ni = 0; ni < 4; ++ni) {
          int d = n0 + wn + ni * 16 + row16;
          out[((size_t)b * 2048 + t) * 256 + d] = f2h(acc[mi][ni][r] + bias[d]);
        }
      }
  } else {
    int m0 = dtile * 128, n0 = blockIdx.x * 128;
    gemm128_glds(wg + (size_t)m0 * 512, 512, X + (size_t)n0 * 512, 512, 512, tid, lA[0], lB[0], acc);
#pragma unroll
    for (int mi = 0; mi < 4; ++mi)
#pragma unroll
      for (int r = 0; r < 4; ++r) {
        int d = m0 + wm + mi * 16 + kg * 4 + r;
        float bias = gb[d];
#pragma unroll
        for (int ni = 0; ni < 4; ++ni) {
          int t = n0 + wn + ni * 16 + row16;
          gv[((size_t)b * 256 + d) * 2048 + t] = f2h(acc[mi][ni][r] + bias);
        }
      }
  }
}

// ---------------- K5: flash attention (512 thr, single 64KB K/V buffer, register
// prefetch, defer-max)
__global__ __launch_bounds__(512) void k_attn(const _Float16* __restrict__ tht,
                                              const _Float16* __restrict__ pht,
                                              const _Float16* __restrict__ gv,
                                              _Float16* __restrict__ yp,
                                              float* __restrict__ mlm, float* __restrict__ mll) {
  int b = blockIdx.z, sp = blockIdx.y;
  int tid = threadIdx.x;
  int wid = tid >> 6, lane = tid & 63;
  int q0 = blockIdx.x * 128 + wid * 16;
  int row16 = lane & 15, kg = lane >> 4, koff = kg * 8;
  int rswz = row16 & 7;

  __shared__ __align__(16) _Float16 kvbuf[32768];
  __shared__ __align__(16) _Float16 p_lds[8][1024];
  char* pw = (char*)&p_lds[wid][0];
  char* cb = (char*)&kvbuf[0];

  const _Float16* thb = tht + (size_t)b * 2048 * 256;
  const _Float16* phb = pht + (size_t)b * 2048 * 256;
  const _Float16* gvb = gv + (size_t)b * 256 * 2048;

  h8v qf[8];
#pragma unroll
  for (int ks = 0; ks < 8; ++ks)
    qf[ks] = *(const h8v*)(thb + (size_t)(q0 + row16) * 256 + ks * 32 + koff);

  float m_i[4], l_i[4];
#pragma unroll
  for (int r = 0; r < 4; ++r) { m_i[r] = -3e38f; l_i[r] = 0.f; }
  f4v yacc[16];
#pragma unroll
  for (int ni = 0; ni < 16; ++ni) yacc[ni] = (f4v){0.f, 0.f, 0.f, 0.f};

  {
    int k0 = sp * 1024;
#pragma unroll
    for (int j = 0; j < 4; ++j) {
      int idx = tid + 512 * j;
      h8v kv = *(const h8v*)(phb + (size_t)(k0 + (idx >> 5)) * 256 + (idx & 31) * 8);
      h8v vv = *(const h8v*)(gvb + (size_t)(idx >> 3) * 2048 + k0 + (idx & 7) * 8);
      *(h8v*)(cb + (idx >> 5) * 512 + (((idx & 31) ^ ((idx >> 5) & 7)) << 4)) = kv;
      *(h8v*)(cb + 32768 + (idx >> 3) * 128 + (((idx & 7) ^ ((idx >> 3) & 7)) << 4)) = vv;
    }
  }
  __syncthreads();

  for (int t = 0; t < 16; ++t) {
    int k0 = sp * 1024 + t * 64;

    h8v kreg[4], vreg[4];
    bool pf = (t < 15);
    if (pf) {
      int k1 = k0 + 64;
#pragma unroll
      for (int j = 0; j < 4; ++j) {
        int idx = tid + 512 * j;
        kreg[j] = *(const h8v*)(phb + (size_t)(k1 + (idx >> 5)) * 256 + (idx & 31) * 8);
        vreg[j] = *(const h8v*)(gvb + (size_t)(idx >> 3) * 2048 + k1 + (idx & 7) * 8);
      }
    }

    f4v sacc[4];
#pragma unroll
    for (int ni = 0; ni < 4; ++ni) sacc[ni] = (f4v){0.f, 0.f, 0.f, 0.f};
#pragma unroll
    for (int ks = 0; ks < 8; ++ks) {
#pragma unroll
      for (int ni = 0; ni < 4; ++ni) {
        int krow = ni * 16 + row16;
        h8v kf = *(const h8v*)(cb + krow * 512 + ((((ks << 2) | kg) ^ rswz) << 4));
        sacc[ni] = MFMA(qf[ks], kf, sacc[ni]);
      }
    }
    float al[4] = {1.f, 1.f, 1.f, 1.f};
    float rmv[4];
    float nd = 0.f;
#pragma unroll
    for (int r = 0; r < 4; ++r) {
      float rm = fmaxf(fmaxf(sacc[0][r], sacc[1][r]), fmaxf(sacc[2][r], sacc[3][r]));
#pragma unroll
      for (int m = 1; m <= 8; m <<= 1) rm = fmaxf(rm, __shfl_xor(rm, m, 64));
      rmv[r] = rm;
      if (rm > m_i[r] + 8.f) nd = 1.f;
    }
    if (__any(nd != 0.f)) {
#pragma unroll
      for (int r = 0; r < 4; ++r) {
        float mn = fmaxf(m_i[r], rmv[r]);
        al[r] = __expf(m_i[r] - mn);
        m_i[r] = mn;
      }
#pragma unroll
      for (int ni = 0; ni < 16; ++ni)
#pragma unroll
        for (int r = 0; r < 4; ++r) yacc[ni][r] *= al[r];
    }
#pragma unroll
    for (int r = 0; r < 4; ++r) {
      float rs = 0.f;
#pragma unroll
      for (int ni = 0; ni < 4; ++ni) {
        float p = __expf(sacc[ni][r] - m_i[r]);
        sacc[ni][r] = p;
        rs += p;
      }
#pragma unroll
      for (int m = 1; m <= 8; m <<= 1) rs += __shfl_xor(rs, m, 64);
      l_i[r] = l_i[r] * al[r] + rs;
    }
#pragma unroll
    for (int r = 0; r < 4; ++r) {
      int q = kg * 4 + r;
#pragma unroll
      for (int ni = 0; ni < 4; ++ni) {
        int sx = ni * 16 + row16;
        *(_Float16*)(pw + pswb(q, sx * 2)) = f2h(sacc[ni][r]);
      }
    }
#pragma unroll
    for (int ks2 = 0; ks2 < 2; ++ks2) {
      h8v pa = *(const h8v*)(pw + pswb(row16, (ks2 * 32 + koff) * 2));
#pragma unroll
      for (int ni = 0; ni < 16; ++ni) {
        int d = ni * 16 + row16;
        h8v vb = *(const h8v*)(cb + 32768 + d * 128 + ((((ks2 << 2) | kg) ^ rswz) << 4));
        yacc[ni] = MFMA(pa, vb, yacc[ni]);
      }
    }
    if (pf) {
      __syncthreads();
#pragma unroll
      for (int j = 0; j < 4; ++j) {
        int idx = tid + 512 * j;
        *(h8v*)(cb + (idx >> 5) * 512 + (((idx & 31) ^ ((idx >> 5) & 7)) << 4)) = kreg[j];
        *(h8v*)(cb + 32768 + (idx >> 3) * 128 + (((idx & 7) ^ ((idx >> 3) & 7)) << 4)) = vreg[j];
      }
      __syncthreads();
    }
  }

  _Float16* yb = yp + (size_t)(sp * 8 + b) * 2048 * 256;
  float* mm = mlm + (size_t)(sp * 8 + b) * 2048;
  float* ml = mll + (size_t)(sp * 8 + b) * 2048;
#pragma unroll
  for (int r = 0; r < 4; ++r) {
    int q = q0 + kg * 4 + r;
#pragma unroll
    for (int ni = 0; ni < 16; ++ni)
      yb[(size_t)q * 256 + ni * 16 + row16] = f2h(yacc[ni][r]);
    if (row16 == 0) { mm[q] = m_i[r]; ml[q] = l_i[r]; }
  }
}

// ---------------- K6: out = BN(W@y + Wb) + x2, combine fused; A via gload_lds
__global__ __launch_bounds__(256, 3) void k_final(const _Float16* __restrict__ Wh,
                                                  const _Float16* __restrict__ yp,
                                                  const float* __restrict__ mlm, const float* __restrict__ mll,
                                                  const float* __restrict__ Wb,
                                                  const float* __restrict__ bng, const float* __restrict__ bnb,
                                                  const float* __restrict__ bnm, const float* __restrict__ bnv,
                                                  const _Float16* __restrict__ x2ct, float* __restrict__ out) {
  int b = blockIdx.z;
  int o0 = blockIdx.y * 128, t0 = blockIdx.x * 128;
  int tid = threadIdx.x;
  int wid = tid >> 6, lane = tid & 63;
  int wm = (wid >> 1) * 64, wn = (wid & 1) * 64;
  int row16 = lane & 15, kg = lane >> 4;
  __shared__ __align__(16) char lA[2][8192];
  __shared__ __align__(16) char lB[2][8192];
  f4v acc[4][4];
#pragma unroll
  for (int mi = 0; mi < 4; ++mi)
#pragma unroll
    for (int ni = 0; ni < 4; ++ni) acc[mi][ni] = (f4v){0.f, 0.f, 0.f, 0.f};

  const _Float16* L = Wh + (size_t)o0 * 256;
  const _Float16* Y0 = yp + ((size_t)b * 2048 + t0) * 256;
  const _Float16* Y1 = yp + ((size_t)(8 + b) * 2048 + t0) * 256;
  int ar0 = tid >> 2, ar1 = ar0 + 64, ach = tid & 3;
  int j0 = tid, j1 = tid + 256;
  int gr0 = j0 >> 2, gc0 = (j0 & 3) ^ ((j0 >> 3) & 3);
  int gr1 = j1 >> 2, gc1 = (j1 & 3) ^ ((j1 >> 3) & 3);
  const _Float16* La0 = L + (size_t)gr0 * 256 + gc0 * 8;
  const _Float16* La1 = L + (size_t)gr1 * 256 + gc1 * 8;
  char* dA0 = lA[0] + wid * 1024;
  char* dA1 = lA[0] + 4096 + wid * 1024;

  float w0a, w1a, w0b, w1b;
  {
    int qa = t0 + ar0, qb = t0 + ar1;
    float mA0 = mlm[(size_t)b * 2048 + qa], mA1 = mlm[(size_t)(8 + b) * 2048 + qa];
    float Ma = fmaxf(mA0, mA1);
    float e0 = __expf(mA0 - Ma), e1 = __expf(mA1 - Ma);
    float La = e0 * mll[(size_t)b * 2048 + qa] + e1 * mll[(size_t)(8 + b) * 2048 + qa];
    float ia = 1.f / La;
    w0a = e0 * ia; w1a = e1 * ia;
    float mB0 = mlm[(size_t)b * 2048 + qb], mB1 = mlm[(size_t)(8 + b) * 2048 + qb];
    float Mb = fmaxf(mB0, mB1);
    float f0 = __expf(mB0 - Mb), f1 = __expf(mB1 - Mb);
    float Lb = f0 * mll[(size_t)b * 2048 + qb] + f1 * mll[(size_t)(8 + b) * 2048 + qb];
    float ib = 1.f / Lb;
    w0b = f0 * ib; w1b = f1 * ib;
  }

  h8v pb0, pb1;
  auto comb = [&](const _Float16* y0, const _Float16* y1, float w0, float w1) -> h8v {
    h8v u = *(const h8v*)y0, v = *(const h8v*)y1, o;
#pragma unroll
    for (int j = 0; j < 8; ++j) o[j] = f2h(w0 * (float)u[j] + w1 * (float)v[j]);
    return o;
  };

  gload16(La0, dA0); gload16(La1, dA1);
  pb0 = comb(Y0 + (size_t)ar0 * 256 + ach * 8, Y1 + (size_t)ar0 * 256 + ach * 8, w0a, w1a);
  pb1 = comb(Y0 + (size_t)ar1 * 256 + ach * 8, Y1 + (size_t)ar1 * 256 + ach * 8, w0b, w1b);
  *(h8v*)(lB[0] + swb(ar0, ach)) = pb0;
  *(h8v*)(lB[0] + swb(ar1, ach)) = pb1;
  __syncthreads();

  for (int kc = 0; kc < 8; ++kc) {
    char* ca = lA[kc & 1];
    char* cbp = lB[kc & 1];
    bool pf = (kc < 7);
    if (pf) {
      int k1 = (kc + 1) << 5;
      int off = ((kc + 1) & 1) * 8192;
      gload16(La0 + k1, dA0 + off); gload16(La1 + k1, dA1 + off);
      pb0 = comb(Y0 + (size_t)ar0 * 256 + k1 + ach * 8, Y1 + (size_t)ar0 * 256 + k1 + ach * 8, w0a, w1a);
      pb1 = comb(Y0 + (size_t)ar1 * 256 + k1 + ach * 8, Y1 + (size_t)ar1 * 256 + k1 + ach * 8, w0b, w1b);
    }
    h8v a[4], bv[4];
#pragma unroll
    for (int i = 0; i < 4; ++i)
      a[i] = *(const h8v*)(ca + swb(wm + i * 16 + row16, kg));
#pragma unroll
    for (int i = 0; i < 4; ++i)
      bv[i] = *(const h8v*)(cbp + swb(wn + i * 16 + row16, kg));
#pragma unroll
    for (int mi = 0; mi < 4; ++mi)
#pragma unroll
      for (int ni = 0; ni < 4; ++ni)
        acc[mi][ni] = MFMA(a[mi], bv[ni], acc[mi][ni]);
    if (pf) {
      char* nb = lB[(kc & 1) ^ 1];
      *(h8v*)(nb + swb(ar0, ach)) = pb0;
      *(h8v*)(nb + swb(ar1, ach)) = pb1;
    }
    __syncthreads();
  }

#pragma unroll
  for (int mi = 0; mi < 4; ++mi)
#pragma unroll
    for (int r = 0; r < 4; ++r) {
      int o = o0 + wm + mi * 16 + kg * 4 + r;
      float sc = bng[o] * rsqrtf(bnv[o] + 1e-5f);
      float add = (Wb[o] - bnm[o]) * sc + bnb[o];
#pragma unroll
      for (int ni = 0; ni < 4; ++ni) {
        int t = t0 + wn + ni * 16 + row16;
        size_t idx = ((size_t)b * 512 + o) * 2048 + t;
        out[idx] = acc[mi][ni][r] * sc + add + (float)x2ct[idx];
      }
    }
}

extern "C" void kernel_launch(void* const* d_in, const int* in_sizes, int n_in,
                              void* d_out, int out_size, void* d_ws, size_t ws_size,
                              hipStream_t stream) {
  const float* x    = (const float*)d_in[0];
  const float* tcw1 = (const float*)d_in[1];
  const float* tcw2 = (const float*)d_in[2];
  const float* zw   = (const float*)d_in[3];
  const float* zb   = (const float*)d_in[4];
  const float* gw   = (const float*)d_in[5];
  const float* gb   = (const float*)d_in[6];
  const float* thw  = (const float*)d_in[7];
  const float* thb  = (const float*)d_in[8];
  const float* phw  = (const float*)d_in[9];
  const float* phb  = (const float*)d_in[10];
  const float* Ww   = (const float*)d_in[11];
  const float* Wb   = (const float*)d_in[12];
  const float* bng  = (const float*)d_in[13];
  const float* bnb  = (const float*)d_in[14];
  const float* bnm  = (const float*)d_in[15];
  const float* bnv  = (const float*)d_in[16];

  char* Wp = (char*)d_ws;
  _Float16* xpe = (_Float16*)(Wp);                  // [b][t][c] f16      16,777,216 B
  _Float16* Mh  = (_Float16*)(Wp + 16777216);       // [5][o][c] f16       2,621,440
  _Float16* x2h = (_Float16*)(Wp + 19398656);       // [b][t][c] f16      16,777,216
  _Float16* x2c = (_Float16*)(Wp + 36175872);       // [b][c][t] f16      16,777,216
  _Float16* tht = (_Float16*)(Wp + 69730304);       // [b][t][d] f16       8,388,608
  _Float16* pht = (_Float16*)(Wp + 78118912);       // [b][t][d] f16       8,388,608
  _Float16* gv  = (_Float16*)(Wp + 86507520);       // [b][d][t] f16       8,388,608
  _Float16* wc  = (_Float16*)(Wp + 103284736);      // 4 x 131072 f16      1,048,576
  _Float16* wth = wc, *wph = wc + 131072, *wg = wc + 262144, *wW = wc + 393216;
  _Float16* zh  = (_Float16*)(Wp + 36175872);                // aliases x2c (dead until k_conv)
  _Float16* wt  = (_Float16*)(Wp + 36175872 + 1572864);
  // attention split scratch aliases xpe/Mh (dead after k_gtp)
  _Float16* yp  = (_Float16*)(Wp);                  // 2x8x2048x256 f16   16,777,216 B
  float*    mlm = (float*)   (Wp + 16777216);       // 2x8x2048 f32          131,072
  float*    mll = (float*)   (Wp + 16908288);       // 2x8x2048 f32          131,072

  k_prep  <<<13696, 256, 0, stream>>>(thw, phw, gw, Ww, zw, tcw1, tcw2, x, wc, zh, wt, xpe);
  k_merge <<<dim3(8, 8, 5), 256, 0, stream>>>(zh, wt, zw, Mh);
  k_conv  <<<dim3(16, 8, 8), 256, 0, stream>>>(Mh, xpe, zb, x2c, x2h);
  k_gtp   <<<dim3(16, 6, 8), 256, 0, stream>>>(x2h, wth, wph, wg, thb, phb, gb, tht, pht, gv);
  k_attn  <<<dim3(16, NSPLIT, 8), 512, 0, stream>>>(tht, pht, gv, yp, mlm, mll);
  k_final <<<dim3(16, 4, 8), 256, 0, stream>>>(wW, yp, mlm, mll, Wb, bng, bnb, bnm, bnv, x2c, (float*)d_out);
}